// Round 16
// baseline (310.009 us; speedup 1.0000x reference)
//
#include <hip/hip_runtime.h>
#include <math.h>

#define NN 50000
#define NE 800000
#define NB 196   // scan blocks (196*256 >= NN)
#define TE 128   // edges per k1 block

typedef __attribute__((ext_vector_type(8))) short short8v;
typedef __attribute__((ext_vector_type(4))) float f32x4;

__device__ __forceinline__ unsigned short f2bf(float f) {
  unsigned u = __float_as_uint(f);
  u += 0x7FFFu + ((u >> 16) & 1u);
  return (unsigned short)(u >> 16);
}
__device__ __forceinline__ unsigned pk2(float a, float b) {
  return (unsigned)f2bf(a) | ((unsigned)f2bf(b) << 16);
}
__device__ __forceinline__ float bflo(unsigned u) { return __uint_as_float(u << 16); }
__device__ __forceinline__ float bfhi(unsigned u) { return __uint_as_float(u & 0xFFFF0000u); }

// ---------------------------------------------------------------------------
// merged prep: blocks [0,3125) histogram edge_i; blocks [3125,3197) pack weights
__global__ void kprep(const int* __restrict__ ei, int* __restrict__ cnt,
                      const float* __restrict__ We1, const float* __restrict__ We2,
                      const float* __restrict__ Wx1, const float* __restrict__ Wh1,
                      const float* __restrict__ Wh2,
                      unsigned short* __restrict__ We1p, unsigned short* __restrict__ We2p,
                      unsigned short* __restrict__ Wx1p, unsigned short* __restrict__ Wh1p,
                      unsigned short* __restrict__ Wh2p) {
  const int b = blockIdx.x;
  if (b < NE / 256) {
    const int i = b * 256 + threadIdx.x;
    atomicAdd(&cnt[ei[i]], 1);
    return;
  }
  const int t = (b - NE / 256) * 256 + threadIdx.x;   // 0..18431
  const int j = t & 7, lane = (t >> 3) & 63;
  const int kk = (lane >> 4) * 8 + j;
  const int nn = lane & 15;
  {  // We1p: K=96, N=192 (combined [top|bot])
    const int tile = t >> 9, tk = tile / 12, tn = tile % 12;
    const int k = tk * 32 + kk, n2 = tn * 16 + nn;
    const float v = (n2 < 96) ? We1[k * 96 + n2] : We1[(96 + k) * 96 + (n2 - 96)];
    We1p[t] = f2bf(v);
  }
  {  // Wh1p: K=192, N=96
    const int tile = t >> 9, tk = tile / 6, tn = tile % 6;
    const int k = tk * 32 + kk, n = tn * 16 + nn;
    Wh1p[t] = f2bf(Wh1[k * 96 + n]);
  }
  if (t < 9216) {  // We2p / Wx1p / Wh2p: K=96, N=96
    const int tile = t >> 9, tk = tile / 6, tn = tile % 6;
    const int k = tk * 32 + kk, n = tn * 16 + nn;
    We2p[t] = f2bf(We2[k * 96 + n]);
    Wx1p[t] = f2bf(Wx1[k * 96 + n]);
    Wh2p[t] = f2bf(Wh2[k * 96 + n]);
  }
}

// scan A: per-block local exclusive scan + block sums
__global__ void kscanA(const int* __restrict__ cnt, int* __restrict__ pre,
                       int* __restrict__ bsum) {
  __shared__ int ps[256];
  const int b = blockIdx.x, t = threadIdx.x, idx = b * 256 + t;
  const int v = (idx < NN) ? cnt[idx] : 0;
  ps[t] = v;
  __syncthreads();
  for (int off = 1; off < 256; off <<= 1) {
    const int u = (t >= off) ? ps[t - off] : 0;
    __syncthreads();
    ps[t] += u;
    __syncthreads();
  }
  if (idx < NN) pre[idx] = ps[t] - v;
  if (t == 255) bsum[b] = ps[255];
}

// fused scan B+C: each block recomputes its block-offset from the 196 bsums
__global__ void kscanBC(const int* __restrict__ pre, const int* __restrict__ bsum,
                        int* __restrict__ base, int* __restrict__ cursor) {
  __shared__ int ws[4];
  const int b = blockIdx.x, t = threadIdx.x;
  int s = (t < b) ? bsum[t] : 0;   // b <= 195 < 256
  s += __shfl_xor(s, 1);  s += __shfl_xor(s, 2);  s += __shfl_xor(s, 4);
  s += __shfl_xor(s, 8);  s += __shfl_xor(s, 16); s += __shfl_xor(s, 32);
  if ((t & 63) == 0) ws[t >> 6] = s;
  __syncthreads();
  const int boff = ws[0] + ws[1] + ws[2] + ws[3];
  const int idx = b * 256 + t;
  if (idx < NN) {
    const int v = pre[idx] + boff;
    base[idx] = v;
    cursor[idx] = v;
  }
  if (idx == 0) base[NN] = NE;
}

// sort edges by vi into int2 pairs; also zeroes WMv/SvM (saves a memset dispatch)
__global__ void kperm(const int* __restrict__ ei, const int* __restrict__ ej,
                      int* __restrict__ cursor, int2* __restrict__ ep,
                      float* __restrict__ wz) {
  const int i = blockIdx.x * 256 + threadIdx.x;
  if (i < 625000) {   // 5,000,000 floats = WMv(4.8M) + SvM(0.2M), contiguous
    const float4 z = make_float4(0.f, 0.f, 0.f, 0.f);
    *(float4*)(wz + (size_t)i * 8) = z;
    *(float4*)(wz + (size_t)i * 8 + 4) = z;
  }
  const int vi = ei[i];
  const int pos = atomicAdd(&cursor[vi], 1);
  ep[pos] = make_int2(vi, ej[i]);
}

// ---------------------------------------------------------------------------
// K0 (MFMA): [A|B] = h @ [We1_top | We1_bot], bf16 out; be1 folded into A.
__global__ __launch_bounds__(256, 4) void k0_AB(const float* __restrict__ h,
                                                const unsigned short* __restrict__ We1p,
                                                const float* __restrict__ be1,
                                                unsigned short* __restrict__ Abf,
                                                unsigned short* __restrict__ Bbf) {
  __shared__ __align__(16) unsigned short hbT[64 * 104];
  __shared__ __align__(16) unsigned short outT[64 * 200];
  const int tid = threadIdx.x;
  const int nb = blockIdx.x * 64;
  {
    const int e = tid & 63, q = tid >> 6;
    const int node = nb + e;
    const int nc = node < NN ? node : NN - 1;
    const float* hr = h + (long)nc * 96 + q * 24;
    unsigned* dst = (unsigned*)hbT + e * 52 + q * 12;
    #pragma unroll
    for (int c = 0; c < 6; ++c) {
      const float4 v = *(const float4*)(hr + c * 4);
      dst[c * 2]     = pk2(v.x, v.y);
      dst[c * 2 + 1] = pk2(v.z, v.w);
    }
  }
  __syncthreads();
  const int l = tid & 63, w = tid >> 6, cg = l & 15, rg = l >> 4;
  {
    const short8v* Wp = (const short8v*)We1p;
    const unsigned short* ar = hbT + (w * 16 + cg) * 104;
    const short8v af0 = *(const short8v*)(ar + rg * 8);
    const short8v af1 = *(const short8v*)(ar + 32 + rg * 8);
    const short8v af2 = *(const short8v*)(ar + 64 + rg * 8);
    #pragma unroll
    for (int tn = 0; tn < 12; ++tn) {
      f32x4 acc = (f32x4){0.f, 0.f, 0.f, 0.f};
      acc = __builtin_amdgcn_mfma_f32_16x16x32_bf16(af0, Wp[(0 * 12 + tn) * 64 + l], acc, 0, 0, 0);
      acc = __builtin_amdgcn_mfma_f32_16x16x32_bf16(af1, Wp[(1 * 12 + tn) * 64 + l], acc, 0, 0, 0);
      acc = __builtin_amdgcn_mfma_f32_16x16x32_bf16(af2, Wp[(2 * 12 + tn) * 64 + l], acc, 0, 0, 0);
      const float bb = (tn < 6) ? be1[tn * 16 + cg] : 0.f;   // fold be1 into A half
      #pragma unroll
      for (int r = 0; r < 4; ++r)
        outT[(w * 16 + rg * 4 + r) * 200 + tn * 16 + cg] = f2bf(acc[r] + bb);
    }
  }
  __syncthreads();
  {
    const int e = tid & 63, q = tid >> 6;
    const int node = nb + e;
    if (node < NN) {
      const unsigned* src = (const unsigned*)outT + e * 100;
      if (q < 2) {
        uint4* dA = (uint4*)(Abf + (size_t)node * 96);
        #pragma unroll
        for (int i = 0; i < 6; ++i) dA[q * 6 + i] = *(const uint4*)(src + (q * 6 + i) * 4);
      } else {
        uint4* dB = (uint4*)(Bbf + (size_t)node * 96);
        #pragma unroll
        for (int i = 0; i < 6; ++i) dB[(q - 2) * 6 + i] = *(const uint4*)(src + 48 + ((q - 2) * 6 + i) * 4);
      }
    }
  }
}

// ---------------------------------------------------------------------------
// K1: 128 sorted edges/block. h1 built DIRECTLY in MFMA A-fragments (no LDS
// round-trip, no phase-0 barrier); m -> LDS for GEMM3 + reduction.
__global__ __launch_bounds__(256, 5) void k1_edge(const float* __restrict__ x,
    const unsigned short* __restrict__ Abf, const unsigned short* __restrict__ Bbf,
    const int2* __restrict__ ep,
    const float* __restrict__ We1,
    const unsigned short* __restrict__ We2p, const float* __restrict__ be2,
    const float* __restrict__ Wm, const float* __restrict__ bm,
    const unsigned short* __restrict__ Wx1p, const float* __restrict__ bx1,
    const float* __restrict__ Wx2,
    float* __restrict__ wmo, float* __restrict__ svo) {
  __shared__ __align__(16) unsigned short actT[TE * 104];   // m only
  __shared__ float gl[TE];
  __shared__ float phil[TE];
  __shared__ __align__(16) float xjl[TE * 4];
  __shared__ float pnl[TE], ppl[TE];
  __shared__ int vseq[TE + 2];
  __shared__ int vjl[TE];
  __shared__ unsigned long long bmask[2];

  const int tid = threadIdx.x;
  const float bm0 = bm[0];
  const int tb = blockIdx.x * TE;

  // ---- pre-phase (short): indices, x gather, psi
  if (tid < TE) {
    const int2 v2 = ep[tb + tid];
    const int vi = v2.x, vj = v2.y;
    vseq[1 + tid] = vi;
    vjl[tid] = vj;
    const float4 xi = *(const float4*)(x + (long)vi * 4);
    const float4 xj = *(const float4*)(x + (long)vj * 4);
    *(float4*)(xjl + tid * 4) = xj;
    const float d0 = xi.x - xj.x, d1 = xi.y - xj.y, d2 = xi.z - xj.z, d3 = xi.w - xj.w;
    const float nrm = d0 * d0 - d1 * d1 - d2 * d2 - d3 * d3;
    const float prd = xi.x * xj.x - xi.y * xj.y - xi.z * xj.z - xi.w * xj.w;
    pnl[tid] = copysignf(logf(fabsf(nrm) + 1.f), nrm);
    ppl[tid] = copysignf(logf(fabsf(prd) + 1.f), prd);
    if (tid == 0) {
      vseq[0] = (tb > 0) ? ep[tb - 1].x : -1;
      vseq[TE + 1] = (tb + TE < NE) ? ep[tb + TE].x : -1;
    }
  }
  __syncthreads();

  // ---- run-end boundary mask via ballot (waves 0,1)
  if (tid < TE) {
    const int pred = (vseq[1 + tid] != vseq[2 + tid]) ? 1 : 0;
    const unsigned long long mk = __ballot(pred);
    if ((tid & 63) == 0) bmask[tid >> 6] = mk;
  }

  const int l = tid & 63, w = tid >> 6;
  const int cg = l & 15, rg = l >> 4;
  const int r0 = w * 32;
  const short8v* Wp2 = (const short8v*)We2p;
  const short8v* Wpx = (const short8v*)Wx1p;

  // ---- GEMM1-in-registers: build h1 A-fragments directly, then GEMM2
  {
    short8v af[2][3];
    #pragma unroll
    for (int rt = 0; rt < 2; ++rt) {
      const int e = r0 + rt * 16 + cg;
      const int vi = vseq[1 + e], vj = vjl[e];
      const float pn = pnl[e], pp = ppl[e];
      #pragma unroll
      for (int tk = 0; tk < 3; ++tk) {
        const int fb = tk * 32 + rg * 8;
        const uint4 a4 = *(const uint4*)(Abf + (size_t)vi * 96 + fb);
        const uint4 b4 = *(const uint4*)(Bbf + (size_t)vj * 96 + fb);
        const float* wA = We1 + 192 * 96 + fb;
        const float* wB = We1 + 193 * 96 + fb;
        const unsigned au[4] = {a4.x, a4.y, a4.z, a4.w};
        const unsigned bu[4] = {b4.x, b4.y, b4.z, b4.w};
        unsigned pkd[4];
        #pragma unroll
        for (int p = 0; p < 4; ++p) {
          const int f = 2 * p;
          const float lo = fmaxf(bflo(au[p]) + bflo(bu[p]) + pn * wA[f] + pp * wB[f], 0.f);
          const float hi = fmaxf(bfhi(au[p]) + bfhi(bu[p]) + pn * wA[f + 1] + pp * wB[f + 1], 0.f);
          pkd[p] = pk2(lo, hi);
        }
        short8v fr;
        fr[0] = (short)(pkd[0] & 0xFFFF); fr[1] = (short)(pkd[0] >> 16);
        fr[2] = (short)(pkd[1] & 0xFFFF); fr[3] = (short)(pkd[1] >> 16);
        fr[4] = (short)(pkd[2] & 0xFFFF); fr[5] = (short)(pkd[2] >> 16);
        fr[6] = (short)(pkd[3] & 0xFFFF); fr[7] = (short)(pkd[3] >> 16);
        af[rt][tk] = fr;
      }
    }

    // ---- GEMM2: m = relu(h1 @ We2 + be2); gate
    f32x4 acc[2][6];
    #pragma unroll
    for (int rt = 0; rt < 2; ++rt)
      #pragma unroll
      for (int tn = 0; tn < 6; ++tn) acc[rt][tn] = (f32x4){0.f, 0.f, 0.f, 0.f};
    #pragma unroll
    for (int tk = 0; tk < 3; ++tk)
      #pragma unroll
      for (int tn = 0; tn < 6; ++tn) {
        const short8v bf = Wp2[(tk * 6 + tn) * 64 + l];
        acc[0][tn] = __builtin_amdgcn_mfma_f32_16x16x32_bf16(af[0][tk], bf, acc[0][tn], 0, 0, 0);
        acc[1][tn] = __builtin_amdgcn_mfma_f32_16x16x32_bf16(af[1][tk], bf, acc[1][tn], 0, 0, 0);
      }
    #pragma unroll
    for (int rt = 0; rt < 2; ++rt) {
      float gp[4] = {0.f, 0.f, 0.f, 0.f};
      #pragma unroll
      for (int tn = 0; tn < 6; ++tn) {
        const int col = tn * 16 + cg;
        const float b = be2[col], wmw = Wm[col];
        #pragma unroll
        for (int r = 0; r < 4; ++r) {
          const float v = fmaxf(acc[rt][tn][r] + b, 0.f);
          gp[r] = fmaf(v, wmw, gp[r]);
          actT[(r0 + rt * 16 + rg * 4 + r) * 104 + col] = (unsigned short)f2bf(v);
        }
      }
      #pragma unroll
      for (int r = 0; r < 4; ++r) {
        float s = gp[r];
        s += __shfl_xor(s, 1); s += __shfl_xor(s, 2);
        s += __shfl_xor(s, 4); s += __shfl_xor(s, 8);
        if (cg == 0) gl[r0 + rt * 16 + rg * 4 + r] = 1.f / (1.f + expf(-(s + bm0)));
      }
    }
  }

  // no barrier: each wave reads only its own rows (m written by itself)

  // ---- GEMM3: phi = relu(m @ Wx1 + bx1) . Wx2
  {
    short8v af[2][3];
    #pragma unroll
    for (int rt = 0; rt < 2; ++rt)
      #pragma unroll
      for (int tk = 0; tk < 3; ++tk)
        af[rt][tk] = *(const short8v*)(actT + (r0 + rt * 16 + cg) * 104 + tk * 32 + rg * 8);
    f32x4 acc[2][6];
    #pragma unroll
    for (int rt = 0; rt < 2; ++rt)
      #pragma unroll
      for (int tn = 0; tn < 6; ++tn) acc[rt][tn] = (f32x4){0.f, 0.f, 0.f, 0.f};
    #pragma unroll
    for (int tk = 0; tk < 3; ++tk)
      #pragma unroll
      for (int tn = 0; tn < 6; ++tn) {
        const short8v bf = Wpx[(tk * 6 + tn) * 64 + l];
        acc[0][tn] = __builtin_amdgcn_mfma_f32_16x16x32_bf16(af[0][tk], bf, acc[0][tn], 0, 0, 0);
        acc[1][tn] = __builtin_amdgcn_mfma_f32_16x16x32_bf16(af[1][tk], bf, acc[1][tn], 0, 0, 0);
      }
    #pragma unroll
    for (int rt = 0; rt < 2; ++rt) {
      float pp2[4] = {0.f, 0.f, 0.f, 0.f};
      #pragma unroll
      for (int tn = 0; tn < 6; ++tn) {
        const int col = tn * 16 + cg;
        const float b = bx1[col], wxw = Wx2[col];
        #pragma unroll
        for (int r = 0; r < 4; ++r)
          pp2[r] = fmaf(fmaxf(acc[rt][tn][r] + b, 0.f), wxw, pp2[r]);
      }
      #pragma unroll
      for (int r = 0; r < 4; ++r) {
        float s = pp2[r];
        s += __shfl_xor(s, 1); s += __shfl_xor(s, 2);
        s += __shfl_xor(s, 4); s += __shfl_xor(s, 8);
        if (cg == 0) phil[r0 + rt * 16 + rg * 4 + r] = s;
      }
    }
  }
  __syncthreads();

  // ---- fused segmented reduction: 48 col-pairs x 4 quarters, b32 reads
  if (tid < 192) {
    const int p = tid % 48;          // column pair: cols 2p, 2p+1
    const int q = tid / 48;          // quarter: edges [q*32, q*32+32)
    const int s_lo = q * 32;
    const unsigned long long mk = bmask[s_lo >> 6];
    float a0 = 0.f, a1 = 0.f;
    bool clean = (q == 0) ? (vseq[0] != vseq[1])
                          : (((bmask[(s_lo - 1) >> 6] >> ((s_lo - 1) & 63)) & 1ull) != 0);
    for (int i = 0; i < 32; ++i) {
      const int e = s_lo + i;
      const unsigned u = *(const unsigned*)(actT + e * 104 + 2 * p);
      const float g = gl[e];
      a0 = fmaf(g, bflo(u), a0);
      a1 = fmaf(g, bfhi(u), a1);
      const bool gend = ((mk >> (e & 63)) & 1ull) != 0;
      if (gend || i == 31) {
        const int node = vseq[e + 1];
        float* dst = wmo + (size_t)node * 96 + 2 * p;
        if (clean && gend) {
          *(float2*)dst = make_float2(a0, a1);
        } else {
          atomicAdd(dst, a0);
          atomicAdd(dst + 1, a1);
        }
        a0 = a1 = 0.f; clean = true;
      }
    }
  } else if (tid < 224) {
    // x-part: 4 comps x 8 sixteenths(16 edges)
    const int t2 = tid - 192;
    const int comp = t2 & 3, q8 = t2 >> 2;
    const int s_lo = q8 * 16;
    const unsigned long long mk = bmask[s_lo >> 6];
    float acc2 = 0.f;
    bool clean = (q8 == 0) ? (vseq[0] != vseq[1])
                           : (((bmask[(s_lo - 1) >> 6] >> ((s_lo - 1) & 63)) & 1ull) != 0);
    for (int i = 0; i < 16; ++i) {
      const int e = s_lo + i;
      acc2 = fmaf(phil[e], xjl[e * 4 + comp], acc2);
      const bool gend = ((mk >> (e & 63)) & 1ull) != 0;
      if (gend || i == 15) {
        const int node = vseq[e + 1];
        float* dst = svo + (size_t)node * 4 + comp;
        if (clean && gend) *dst = acc2; else atomicAdd(dst, acc2);
        acc2 = 0.f; clean = true;
      }
    }
  }
}

// ---------------------------------------------------------------------------
// K3 fused (MFMA): tmp = relu([h,wm]@Wh1+bh1); h_out = h + tmp@Wh2 + bh2; x_out
__global__ __launch_bounds__(256, 4) void k3ab(const float* __restrict__ h,
    const float* __restrict__ wmv,
    const unsigned short* __restrict__ Wh1p, const float* __restrict__ bh1,
    const unsigned short* __restrict__ Wh2p, const float* __restrict__ bh2,
    const float* __restrict__ x, const float* __restrict__ svm,
    const int* __restrict__ basep,
    float* __restrict__ hout, float* __restrict__ xout) {
  __shared__ __align__(16) unsigned short inT[64 * 200];   // reused as float[64][100]
  __shared__ __align__(16) unsigned short tmpT[64 * 104];
  const int tid = threadIdx.x;
  const int nb = blockIdx.x * 64;
  {
    const int e = tid & 63, q = tid >> 6;
    const int node = nb + e;
    const int nc = node < NN ? node : NN - 1;
    const float* hr = h + (long)nc * 96 + q * 24;
    const float* wr = wmv + (long)nc * 96 + q * 24;
    unsigned* dh = (unsigned*)inT + e * 100 + q * 12;
    unsigned* dw = (unsigned*)inT + e * 100 + 48 + q * 12;
    #pragma unroll
    for (int c = 0; c < 6; ++c) {
      const float4 v = *(const float4*)(hr + c * 4);
      dh[c * 2]     = pk2(v.x, v.y);
      dh[c * 2 + 1] = pk2(v.z, v.w);
      const float4 u = *(const float4*)(wr + c * 4);
      dw[c * 2]     = pk2(u.x, u.y);
      dw[c * 2 + 1] = pk2(u.z, u.w);
    }
  }
  __syncthreads();
  const int l = tid & 63, w = tid >> 6, cg = l & 15, rg = l >> 4;
  {
    const unsigned short* ar = inT + (w * 16 + cg) * 200;
    short8v af[6];
    #pragma unroll
    for (int tk = 0; tk < 6; ++tk) af[tk] = *(const short8v*)(ar + tk * 32 + rg * 8);
    const short8v* Wp = (const short8v*)Wh1p;
    #pragma unroll
    for (int tn = 0; tn < 6; ++tn) {
      f32x4 acc = (f32x4){0.f, 0.f, 0.f, 0.f};
      #pragma unroll
      for (int tk = 0; tk < 6; ++tk)
        acc = __builtin_amdgcn_mfma_f32_16x16x32_bf16(af[tk], Wp[(tk * 6 + tn) * 64 + l], acc, 0, 0, 0);
      const int col = tn * 16 + cg;
      const float b = bh1[col];
      #pragma unroll
      for (int r = 0; r < 4; ++r)
        tmpT[(w * 16 + rg * 4 + r) * 104 + col] = f2bf(fmaxf(acc[r] + b, 0.f));
    }
  }
  __syncthreads();
  {
    float* oT = (float*)inT;
    const unsigned short* mr = tmpT + (w * 16 + cg) * 104;
    const short8v mf0 = *(const short8v*)(mr + rg * 8);
    const short8v mf1 = *(const short8v*)(mr + 32 + rg * 8);
    const short8v mf2 = *(const short8v*)(mr + 64 + rg * 8);
    const short8v* Wp = (const short8v*)Wh2p;
    #pragma unroll
    for (int tn = 0; tn < 6; ++tn) {
      f32x4 acc = (f32x4){0.f, 0.f, 0.f, 0.f};
      acc = __builtin_amdgcn_mfma_f32_16x16x32_bf16(mf0, Wp[(0 * 6 + tn) * 64 + l], acc, 0, 0, 0);
      acc = __builtin_amdgcn_mfma_f32_16x16x32_bf16(mf1, Wp[(1 * 6 + tn) * 64 + l], acc, 0, 0, 0);
      acc = __builtin_amdgcn_mfma_f32_16x16x32_bf16(mf2, Wp[(2 * 6 + tn) * 64 + l], acc, 0, 0, 0);
      const int col = tn * 16 + cg;
      const float b = bh2[col];
      #pragma unroll
      for (int r = 0; r < 4; ++r)
        oT[(w * 16 + rg * 4 + r) * 100 + col] = acc[r] + b;
    }
  }
  __syncthreads();
  {
    const int e = tid & 63, q = tid >> 6;
    const int node = nb + e;
    if (node < NN) {
      const float* src = (const float*)inT + e * 100 + q * 24;
      const float* hr = h + (size_t)node * 96 + q * 24;
      float* dst = hout + (size_t)node * 96 + q * 24;
      #pragma unroll
      for (int c = 0; c < 6; ++c) {
        const float4 s = *(const float4*)(src + c * 4);
        const float4 hv = *(const float4*)(hr + c * 4);
        *(float4*)(dst + c * 4) = make_float4(hv.x + s.x, hv.y + s.y, hv.z + s.z, hv.w + s.w);
      }
    }
  }
  if (tid < 64) {
    const int node = nb + tid;
    if (node < NN) {
      const int cnt = basep[node + 1] - basep[node];
      const float inv = cnt > 0 ? 1.f / (float)cnt : 0.f;
      const float4 s4 = *(const float4*)(svm + (long)node * 4);
      const float4 xv = *(const float4*)(x + (long)node * 4);
      *(float4*)(xout + (long)node * 4) =
          make_float4(xv.x + 0.005f * s4.x * inv, xv.y + 0.005f * s4.y * inv,
                      xv.z + 0.005f * s4.z * inv, xv.w + 0.005f * s4.w * inv);
    }
  }
}

// ---------------------------------------------------------------------------
extern "C" void kernel_launch(void* const* d_in, const int* in_sizes, int n_in,
                              void* d_out, int out_size, void* d_ws, size_t ws_size,
                              hipStream_t stream) {
  const float* x   = (const float*)d_in[0];
  const float* h   = (const float*)d_in[1];
  const int*   ei  = (const int*)d_in[2];
  const int*   ej  = (const int*)d_in[3];
  const float* We1 = (const float*)d_in[4];
  const float* be1 = (const float*)d_in[5];
  const float* We2 = (const float*)d_in[6];
  const float* be2 = (const float*)d_in[7];
  const float* Wm  = (const float*)d_in[8];
  const float* bm  = (const float*)d_in[9];
  const float* Wh1 = (const float*)d_in[10];
  const float* bh1 = (const float*)d_in[11];
  const float* Wh2 = (const float*)d_in[12];
  const float* bh2 = (const float*)d_in[13];
  const float* Wx1 = (const float*)d_in[14];
  const float* bx1 = (const float*)d_in[15];
  const float* Wx2 = (const float*)d_in[16];

  char* w = (char*)d_ws;
  unsigned short* Abf  = (unsigned short*)w;                 //  9.6 MB
  unsigned short* Bbf  = (unsigned short*)(w + 9600000);     //  9.6 MB
  float* WMv  = (float*)(w + 19200000);                      // 19.2 MB
  float* SvM  = (float*)(w + 38400000);                      //  0.8 MB (contiguous after WMv)
  int*   cnt  = (int*)(w + 39200000);                        //  0.2 MB
  int*   base = (int*)(w + 39400000);                        //  0.2 MB (+4)
  int*   curs = (int*)(w + 39600064);                        //  0.2 MB
  unsigned short* We2p = (unsigned short*)(w + 39800064);    // 18 KB
  unsigned short* Wx1p = (unsigned short*)(w + 39818496);    // 18 KB
  unsigned short* We1p = (unsigned short*)(w + 39836928);    // 36 KB
  unsigned short* Wh1p = (unsigned short*)(w + 39873792);    // 36 KB
  unsigned short* Wh2p = (unsigned short*)(w + 39910656);    // 18 KB
  int2*  epb  = (int2*)(w + 39929088);                       //  6.4 MB
  int*   pre  = (int*)(w + 46329088);                        //  0.2 MB
  int*   bsum = (int*)(w + 46529088);                        //  784 B

  float* hout = (float*)d_out;
  float* xout = hout + 4800000;

  hipMemsetAsync(cnt, 0, NN * sizeof(int), stream);
  kprep<<<NE / 256 + 72, 256, 0, stream>>>(ei, cnt, We1, We2, Wx1, Wh1, Wh2,
                                           We1p, We2p, Wx1p, Wh1p, Wh2p);
  kscanA<<<NB, 256, 0, stream>>>(cnt, pre, bsum);
  kscanBC<<<NB, 256, 0, stream>>>(pre, bsum, base, curs);
  kperm<<<NE / 256, 256, 0, stream>>>(ei, ej, curs, epb, WMv);
  k0_AB<<<782, 256, 0, stream>>>(h, We1p, be1, Abf, Bbf);
  k1_edge<<<NE / TE, 256, 0, stream>>>(x, Abf, Bbf, epb, We1, We2p, be2,
                                       Wm, bm, Wx1p, bx1, Wx2, WMv, SvM);
  k3ab<<<782, 256, 0, stream>>>(h, WMv, Wh1p, bh1, Wh2p, bh2, x, SvM, base, hout, xout);
}

// Round 18
// 271.751 us; speedup vs baseline: 1.1408x; 1.1408x over previous
//
#include <hip/hip_runtime.h>
#include <math.h>

#define NN 50000
#define NE 800000
#define NB 196   // scan blocks (196*256 >= NN)
#define TE 128   // edges per k1 block

typedef __attribute__((ext_vector_type(8))) _Float16 half8v;
typedef __attribute__((ext_vector_type(2))) _Float16 half2v;
typedef __attribute__((ext_vector_type(4))) float f32x4;

__device__ __forceinline__ unsigned short f2h_us(float f) {
  const _Float16 h = (_Float16)f;
  return *(const unsigned short*)&h;
}
__device__ __forceinline__ unsigned pk2h(float a, float b) {
  half2v h; h[0] = (_Float16)a; h[1] = (_Float16)b;
  return *(unsigned*)&h;
}

// ---------------------------------------------------------------------------
// merged prep: blocks [0,3125) histogram edge_i; blocks [3125,3197) pack weights
__global__ void kprep(const int* __restrict__ ei, int* __restrict__ cnt,
                      const float* __restrict__ We1, const float* __restrict__ We2,
                      const float* __restrict__ Wx1, const float* __restrict__ Wh1,
                      const float* __restrict__ Wh2,
                      unsigned short* __restrict__ We1p, unsigned short* __restrict__ We2p,
                      unsigned short* __restrict__ Wx1p, unsigned short* __restrict__ Wh1p,
                      unsigned short* __restrict__ Wh2p, unsigned* __restrict__ WA2,
                      unsigned* __restrict__ WB2) {
  const int b = blockIdx.x;
  if (b < NE / 256) {
    const int i = b * 256 + threadIdx.x;
    atomicAdd(&cnt[ei[i]], 1);
    return;
  }
  const int t = (b - NE / 256) * 256 + threadIdx.x;   // 0..18431
  const int j = t & 7, lane = (t >> 3) & 63;
  const int kk = (lane >> 4) * 8 + j;
  const int nn = lane & 15;
  {  // We1p: K=96, N=192 (combined [top|bot])
    const int tile = t >> 9, tk = tile / 12, tn = tile % 12;
    const int k = tk * 32 + kk, n2 = tn * 16 + nn;
    const float v = (n2 < 96) ? We1[k * 96 + n2] : We1[(96 + k) * 96 + (n2 - 96)];
    We1p[t] = f2h_us(v);
  }
  {  // Wh1p: K=192, N=96
    const int tile = t >> 9, tk = tile / 6, tn = tile % 6;
    const int k = tk * 32 + kk, n = tn * 16 + nn;
    Wh1p[t] = f2h_us(Wh1[k * 96 + n]);
  }
  if (t < 9216) {  // We2p / Wx1p / Wh2p: K=96, N=96
    const int tile = t >> 9, tk = tile / 6, tn = tile % 6;
    const int k = tk * 32 + kk, n = tn * 16 + nn;
    We2p[t] = f2h_us(We2[k * 96 + n]);
    Wx1p[t] = f2h_us(Wx1[k * 96 + n]);
    Wh2p[t] = f2h_us(Wh2[k * 96 + n]);
  }
  if (t < 48) {  // psi weight rows as half2 pairs
    WA2[t] = pk2h(We1[192 * 96 + 2 * t], We1[192 * 96 + 2 * t + 1]);
    WB2[t] = pk2h(We1[193 * 96 + 2 * t], We1[193 * 96 + 2 * t + 1]);
  }
}

// scan A: per-block local exclusive scan + block sums
__global__ void kscanA(const int* __restrict__ cnt, int* __restrict__ pre,
                       int* __restrict__ bsum) {
  __shared__ int ps[256];
  const int b = blockIdx.x, t = threadIdx.x, idx = b * 256 + t;
  const int v = (idx < NN) ? cnt[idx] : 0;
  ps[t] = v;
  __syncthreads();
  for (int off = 1; off < 256; off <<= 1) {
    const int u = (t >= off) ? ps[t - off] : 0;
    __syncthreads();
    ps[t] += u;
    __syncthreads();
  }
  if (idx < NN) pre[idx] = ps[t] - v;
  if (t == 255) bsum[b] = ps[255];
}

// fused scan B+C: each block recomputes its block-offset from the 196 bsums
__global__ void kscanBC(const int* __restrict__ pre, const int* __restrict__ bsum,
                        int* __restrict__ base, int* __restrict__ cursor) {
  __shared__ int ws[4];
  const int b = blockIdx.x, t = threadIdx.x;
  int s = (t < b) ? bsum[t] : 0;   // b <= 195 < 256
  s += __shfl_xor(s, 1);  s += __shfl_xor(s, 2);  s += __shfl_xor(s, 4);
  s += __shfl_xor(s, 8);  s += __shfl_xor(s, 16); s += __shfl_xor(s, 32);
  if ((t & 63) == 0) ws[t >> 6] = s;
  __syncthreads();
  const int boff = ws[0] + ws[1] + ws[2] + ws[3];
  const int idx = b * 256 + t;
  if (idx < NN) {
    const int v = pre[idx] + boff;
    base[idx] = v;
    cursor[idx] = v;
  }
  if (idx == 0) base[NN] = NE;
}

// sort edges by vi into int2 pairs; also zeroes WMv/SvM (saves a memset dispatch)
__global__ void kperm(const int* __restrict__ ei, const int* __restrict__ ej,
                      int* __restrict__ cursor, int2* __restrict__ ep,
                      float* __restrict__ wz) {
  const int i = blockIdx.x * 256 + threadIdx.x;
  if (i < 625000) {   // 5,000,000 floats = WMv(4.8M) + SvM(0.2M), contiguous
    const float4 z = make_float4(0.f, 0.f, 0.f, 0.f);
    *(float4*)(wz + (size_t)i * 8) = z;
    *(float4*)(wz + (size_t)i * 8 + 4) = z;
  }
  const int vi = ei[i];
  const int pos = atomicAdd(&cursor[vi], 1);
  ep[pos] = make_int2(vi, ej[i]);
}

// ---------------------------------------------------------------------------
// K0 (MFMA f16): [A|B] = h @ [We1_top | We1_bot]; be1 folded into A half.
__global__ __launch_bounds__(256, 4) void k0_AB(const float* __restrict__ h,
                                                const unsigned short* __restrict__ We1p,
                                                const float* __restrict__ be1,
                                                unsigned short* __restrict__ Ahf,
                                                unsigned short* __restrict__ Bhf) {
  __shared__ __align__(16) unsigned short hbT[64 * 104];
  __shared__ __align__(16) unsigned short outT[64 * 200];
  const int tid = threadIdx.x;
  const int nb = blockIdx.x * 64;
  {
    const int e = tid & 63, q = tid >> 6;
    const int node = nb + e;
    const int nc = node < NN ? node : NN - 1;
    const float* hr = h + (long)nc * 96 + q * 24;
    unsigned* dst = (unsigned*)hbT + e * 52 + q * 12;
    #pragma unroll
    for (int c = 0; c < 6; ++c) {
      const float4 v = *(const float4*)(hr + c * 4);
      dst[c * 2]     = pk2h(v.x, v.y);
      dst[c * 2 + 1] = pk2h(v.z, v.w);
    }
  }
  __syncthreads();
  const int l = tid & 63, w = tid >> 6, cg = l & 15, rg = l >> 4;
  {
    const half8v* Wp = (const half8v*)We1p;
    const unsigned short* ar = hbT + (w * 16 + cg) * 104;
    const half8v af0 = *(const half8v*)(ar + rg * 8);
    const half8v af1 = *(const half8v*)(ar + 32 + rg * 8);
    const half8v af2 = *(const half8v*)(ar + 64 + rg * 8);
    #pragma unroll
    for (int tn = 0; tn < 12; ++tn) {
      f32x4 acc = (f32x4){0.f, 0.f, 0.f, 0.f};
      acc = __builtin_amdgcn_mfma_f32_16x16x32_f16(af0, Wp[(0 * 12 + tn) * 64 + l], acc, 0, 0, 0);
      acc = __builtin_amdgcn_mfma_f32_16x16x32_f16(af1, Wp[(1 * 12 + tn) * 64 + l], acc, 0, 0, 0);
      acc = __builtin_amdgcn_mfma_f32_16x16x32_f16(af2, Wp[(2 * 12 + tn) * 64 + l], acc, 0, 0, 0);
      const float bb = (tn < 6) ? be1[tn * 16 + cg] : 0.f;   // fold be1 into A half
      #pragma unroll
      for (int r = 0; r < 4; ++r)
        outT[(w * 16 + rg * 4 + r) * 200 + tn * 16 + cg] = f2h_us(acc[r] + bb);
    }
  }
  __syncthreads();
  {
    const int e = tid & 63, q = tid >> 6;
    const int node = nb + e;
    if (node < NN) {
      const unsigned* src = (const unsigned*)outT + e * 100;
      if (q < 2) {
        uint4* dA = (uint4*)(Ahf + (size_t)node * 96);
        #pragma unroll
        for (int i = 0; i < 6; ++i) dA[q * 6 + i] = *(const uint4*)(src + (q * 6 + i) * 4);
      } else {
        uint4* dB = (uint4*)(Bhf + (size_t)node * 96);
        #pragma unroll
        for (int i = 0; i < 6; ++i) dB[(q - 2) * 6 + i] = *(const uint4*)(src + 48 + ((q - 2) * 6 + i) * 4);
      }
    }
  }
}

// ---------------------------------------------------------------------------
// K1: 128 sorted edges/block (R15 structure); phase-0 in packed fp16 math.
__global__ __launch_bounds__(256, 5) void k1_edge(const float* __restrict__ x,
    const unsigned short* __restrict__ Ahf, const unsigned short* __restrict__ Bhf,
    const int2* __restrict__ ep,
    const unsigned* __restrict__ WA2, const unsigned* __restrict__ WB2,
    const unsigned short* __restrict__ We2p, const float* __restrict__ be2,
    const float* __restrict__ Wm, const float* __restrict__ bm,
    const unsigned short* __restrict__ Wx1p, const float* __restrict__ bx1,
    const float* __restrict__ Wx2,
    float* __restrict__ wmo, float* __restrict__ svo) {
  __shared__ __align__(16) unsigned short actT[TE * 104];
  __shared__ float gl[TE];
  __shared__ float phil[TE];
  __shared__ __align__(16) float xjl[TE * 4];
  __shared__ int vseq[TE + 2];
  __shared__ unsigned long long bmask[2];

  const int tid = threadIdx.x;
  const float bm0 = bm[0];
  const int tb = blockIdx.x * TE;

  // ---- phase 0: gather + h1 (packed fp16; thread: edge e2, feature half hf)
  {
    const int e2 = tid & 127, hf = tid >> 7;
    const int fb = hf * 48;
    const int2 v2 = ep[tb + e2];
    const int vi = v2.x, vj = v2.y;
    const float4 xi = *(const float4*)(x + (long)vi * 4);
    const float4 xj = *(const float4*)(x + (long)vj * 4);
    if (hf == 0) {
      vseq[1 + e2] = vi;
      *(float4*)(xjl + e2 * 4) = xj;
    }
    if (tid == 0) {
      vseq[0] = (tb > 0) ? ep[tb - 1].x : -1;
      vseq[TE + 1] = (tb + TE < NE) ? ep[tb + TE].x : -1;
    }
    const float d0 = xi.x - xj.x, d1 = xi.y - xj.y, d2 = xi.z - xj.z, d3 = xi.w - xj.w;
    const float nrm = d0 * d0 - d1 * d1 - d2 * d2 - d3 * d3;
    const float prd = xi.x * xj.x - xi.y * xj.y - xi.z * xj.z - xi.w * xj.w;
    const float pn = copysignf(logf(fabsf(nrm) + 1.f), nrm);
    const float pp = copysignf(logf(fabsf(prd) + 1.f), prd);
    half2v pn2; pn2[0] = (_Float16)pn; pn2[1] = (_Float16)pn;
    half2v pp2; pp2[0] = (_Float16)pp; pp2[1] = (_Float16)pp;
    const half2v z2 = (half2v){(_Float16)0.f, (_Float16)0.f};
    const uint4* Ar = (const uint4*)(Ahf + (size_t)vi * 96 + fb);
    const uint4* Br = (const uint4*)(Bhf + (size_t)vj * 96 + fb);
    const half2v* wa2 = (const half2v*)(WA2 + fb / 2);
    const half2v* wb2 = (const half2v*)(WB2 + fb / 2);
    unsigned* arow = (unsigned*)actT + e2 * 52 + hf * 24;
    #pragma unroll
    for (int c = 0; c < 6; ++c) {
      const uint4 A4 = Ar[c], B4 = Br[c];
      const half2v* a2 = (const half2v*)&A4;
      const half2v* b2 = (const half2v*)&B4;
      #pragma unroll
      for (int k2 = 0; k2 < 4; ++k2) {
        half2v t = a2[k2] + b2[k2];
        t = pn2 * wa2[c * 4 + k2] + t;
        t = pp2 * wb2[c * 4 + k2] + t;
        t = __builtin_elementwise_max(t, z2);
        arow[c * 4 + k2] = *(unsigned*)&t;
      }
    }
  }
  __syncthreads();

  // ---- run-end boundary mask via ballot (waves 0,1)
  if (tid < TE) {
    const int pred = (vseq[1 + tid] != vseq[2 + tid]) ? 1 : 0;
    const unsigned long long mk = __ballot(pred);
    if ((tid & 63) == 0) bmask[tid >> 6] = mk;
  }

  const int l = tid & 63, w = tid >> 6;
  const int cg = l & 15, rg = l >> 4;
  const int r0 = w * 32;
  const half8v* Wp2 = (const half8v*)We2p;
  const half8v* Wpx = (const half8v*)Wx1p;

  // ---- GEMM2: m = relu(h1 @ We2 + be2); gate
  {
    half8v af[2][3];
    #pragma unroll
    for (int rt = 0; rt < 2; ++rt)
      #pragma unroll
      for (int tk = 0; tk < 3; ++tk)
        af[rt][tk] = *(const half8v*)(actT + (r0 + rt * 16 + cg) * 104 + tk * 32 + rg * 8);
    f32x4 acc[2][6];
    #pragma unroll
    for (int rt = 0; rt < 2; ++rt)
      #pragma unroll
      for (int tn = 0; tn < 6; ++tn) acc[rt][tn] = (f32x4){0.f, 0.f, 0.f, 0.f};
    #pragma unroll
    for (int tk = 0; tk < 3; ++tk)
      #pragma unroll
      for (int tn = 0; tn < 6; ++tn) {
        const half8v bf = Wp2[(tk * 6 + tn) * 64 + l];
        acc[0][tn] = __builtin_amdgcn_mfma_f32_16x16x32_f16(af[0][tk], bf, acc[0][tn], 0, 0, 0);
        acc[1][tn] = __builtin_amdgcn_mfma_f32_16x16x32_f16(af[1][tk], bf, acc[1][tn], 0, 0, 0);
      }
    #pragma unroll
    for (int rt = 0; rt < 2; ++rt) {
      float gp[4] = {0.f, 0.f, 0.f, 0.f};
      #pragma unroll
      for (int tn = 0; tn < 6; ++tn) {
        const int col = tn * 16 + cg;
        const float b = be2[col], wmw = Wm[col];
        #pragma unroll
        for (int r = 0; r < 4; ++r) {
          const float v = fmaxf(acc[rt][tn][r] + b, 0.f);
          gp[r] = fmaf(v, wmw, gp[r]);
          actT[(r0 + rt * 16 + rg * 4 + r) * 104 + col] = f2h_us(v);
        }
      }
      #pragma unroll
      for (int r = 0; r < 4; ++r) {
        float s = gp[r];
        s += __shfl_xor(s, 1); s += __shfl_xor(s, 2);
        s += __shfl_xor(s, 4); s += __shfl_xor(s, 8);
        if (cg == 0) gl[r0 + rt * 16 + rg * 4 + r] = 1.f / (1.f + expf(-(s + bm0)));
      }
    }
  }

  // no barrier: each wave reads only its own rows (m written by itself)

  // ---- GEMM3: phi = relu(m @ Wx1 + bx1) . Wx2
  {
    half8v af[2][3];
    #pragma unroll
    for (int rt = 0; rt < 2; ++rt)
      #pragma unroll
      for (int tk = 0; tk < 3; ++tk)
        af[rt][tk] = *(const half8v*)(actT + (r0 + rt * 16 + cg) * 104 + tk * 32 + rg * 8);
    f32x4 acc[2][6];
    #pragma unroll
    for (int rt = 0; rt < 2; ++rt)
      #pragma unroll
      for (int tn = 0; tn < 6; ++tn) acc[rt][tn] = (f32x4){0.f, 0.f, 0.f, 0.f};
    #pragma unroll
    for (int tk = 0; tk < 3; ++tk)
      #pragma unroll
      for (int tn = 0; tn < 6; ++tn) {
        const half8v bf = Wpx[(tk * 6 + tn) * 64 + l];
        acc[0][tn] = __builtin_amdgcn_mfma_f32_16x16x32_f16(af[0][tk], bf, acc[0][tn], 0, 0, 0);
        acc[1][tn] = __builtin_amdgcn_mfma_f32_16x16x32_f16(af[1][tk], bf, acc[1][tn], 0, 0, 0);
      }
    #pragma unroll
    for (int rt = 0; rt < 2; ++rt) {
      float pp2[4] = {0.f, 0.f, 0.f, 0.f};
      #pragma unroll
      for (int tn = 0; tn < 6; ++tn) {
        const int col = tn * 16 + cg;
        const float b = bx1[col], wxw = Wx2[col];
        #pragma unroll
        for (int r = 0; r < 4; ++r)
          pp2[r] = fmaf(fmaxf(acc[rt][tn][r] + b, 0.f), wxw, pp2[r]);
      }
      #pragma unroll
      for (int r = 0; r < 4; ++r) {
        float s = pp2[r];
        s += __shfl_xor(s, 1); s += __shfl_xor(s, 2);
        s += __shfl_xor(s, 4); s += __shfl_xor(s, 8);
        if (cg == 0) phil[r0 + rt * 16 + rg * 4 + r] = s;
      }
    }
  }
  __syncthreads();

  // ---- fused segmented reduction: 48 col-pairs x 4 quarters, b32 reads
  if (tid < 192) {
    const int p = tid % 48;          // column pair: cols 2p, 2p+1
    const int q = tid / 48;          // quarter: edges [q*32, q*32+32)
    const int s_lo = q * 32;
    const unsigned long long mk = bmask[s_lo >> 6];
    float a0 = 0.f, a1 = 0.f;
    bool clean = (q == 0) ? (vseq[0] != vseq[1])
                          : (((bmask[(s_lo - 1) >> 6] >> ((s_lo - 1) & 63)) & 1ull) != 0);
    for (int i = 0; i < 32; ++i) {
      const int e = s_lo + i;
      const half2v h2 = *(const half2v*)(actT + e * 104 + 2 * p);
      const float g = gl[e];
      a0 = fmaf(g, (float)h2[0], a0);
      a1 = fmaf(g, (float)h2[1], a1);
      const bool gend = ((mk >> (e & 63)) & 1ull) != 0;
      if (gend || i == 31) {
        const int node = vseq[e + 1];
        float* dst = wmo + (size_t)node * 96 + 2 * p;
        if (clean && gend) {
          *(float2*)dst = make_float2(a0, a1);
        } else {
          atomicAdd(dst, a0);
          atomicAdd(dst + 1, a1);
        }
        a0 = a1 = 0.f; clean = true;
      }
    }
  } else if (tid < 224) {
    // x-part: 4 comps x 8 sixteenths(16 edges)
    const int t2 = tid - 192;
    const int comp = t2 & 3, q8 = t2 >> 2;
    const int s_lo = q8 * 16;
    const unsigned long long mk = bmask[s_lo >> 6];
    float acc2 = 0.f;
    bool clean = (q8 == 0) ? (vseq[0] != vseq[1])
                           : (((bmask[(s_lo - 1) >> 6] >> ((s_lo - 1) & 63)) & 1ull) != 0);
    for (int i = 0; i < 16; ++i) {
      const int e = s_lo + i;
      acc2 = fmaf(phil[e], xjl[e * 4 + comp], acc2);
      const bool gend = ((mk >> (e & 63)) & 1ull) != 0;
      if (gend || i == 15) {
        const int node = vseq[e + 1];
        float* dst = svo + (size_t)node * 4 + comp;
        if (clean && gend) *dst = acc2; else atomicAdd(dst, acc2);
        acc2 = 0.f; clean = true;
      }
    }
  }
}

// ---------------------------------------------------------------------------
// K3 fused (MFMA f16): tmp = relu([h,wm]@Wh1+bh1); h_out = h + tmp@Wh2 + bh2; x_out
__global__ __launch_bounds__(256, 4) void k3ab(const float* __restrict__ h,
    const float* __restrict__ wmv,
    const unsigned short* __restrict__ Wh1p, const float* __restrict__ bh1,
    const unsigned short* __restrict__ Wh2p, const float* __restrict__ bh2,
    const float* __restrict__ x, const float* __restrict__ svm,
    const int* __restrict__ basep,
    float* __restrict__ hout, float* __restrict__ xout) {
  __shared__ __align__(16) unsigned short inT[64 * 200];   // reused as float[64][100]
  __shared__ __align__(16) unsigned short tmpT[64 * 104];
  const int tid = threadIdx.x;
  const int nb = blockIdx.x * 64;
  {
    const int e = tid & 63, q = tid >> 6;
    const int node = nb + e;
    const int nc = node < NN ? node : NN - 1;
    const float* hr = h + (long)nc * 96 + q * 24;
    const float* wr = wmv + (long)nc * 96 + q * 24;
    unsigned* dh = (unsigned*)inT + e * 100 + q * 12;
    unsigned* dw = (unsigned*)inT + e * 100 + 48 + q * 12;
    #pragma unroll
    for (int c = 0; c < 6; ++c) {
      const float4 v = *(const float4*)(hr + c * 4);
      dh[c * 2]     = pk2h(v.x, v.y);
      dh[c * 2 + 1] = pk2h(v.z, v.w);
      const float4 u = *(const float4*)(wr + c * 4);
      dw[c * 2]     = pk2h(u.x, u.y);
      dw[c * 2 + 1] = pk2h(u.z, u.w);
    }
  }
  __syncthreads();
  const int l = tid & 63, w = tid >> 6, cg = l & 15, rg = l >> 4;
  {
    const unsigned short* ar = inT + (w * 16 + cg) * 200;
    half8v af[6];
    #pragma unroll
    for (int tk = 0; tk < 6; ++tk) af[tk] = *(const half8v*)(ar + tk * 32 + rg * 8);
    const half8v* Wp = (const half8v*)Wh1p;
    #pragma unroll
    for (int tn = 0; tn < 6; ++tn) {
      f32x4 acc = (f32x4){0.f, 0.f, 0.f, 0.f};
      #pragma unroll
      for (int tk = 0; tk < 6; ++tk)
        acc = __builtin_amdgcn_mfma_f32_16x16x32_f16(af[tk], Wp[(tk * 6 + tn) * 64 + l], acc, 0, 0, 0);
      const int col = tn * 16 + cg;
      const float b = bh1[col];
      #pragma unroll
      for (int r = 0; r < 4; ++r)
        tmpT[(w * 16 + rg * 4 + r) * 104 + col] = f2h_us(fmaxf(acc[r] + b, 0.f));
    }
  }
  __syncthreads();
  {
    float* oT = (float*)inT;
    const unsigned short* mr = tmpT + (w * 16 + cg) * 104;
    const half8v mf0 = *(const half8v*)(mr + rg * 8);
    const half8v mf1 = *(const half8v*)(mr + 32 + rg * 8);
    const half8v mf2 = *(const half8v*)(mr + 64 + rg * 8);
    const half8v* Wp = (const half8v*)Wh2p;
    #pragma unroll
    for (int tn = 0; tn < 6; ++tn) {
      f32x4 acc = (f32x4){0.f, 0.f, 0.f, 0.f};
      acc = __builtin_amdgcn_mfma_f32_16x16x32_f16(mf0, Wp[(0 * 6 + tn) * 64 + l], acc, 0, 0, 0);
      acc = __builtin_amdgcn_mfma_f32_16x16x32_f16(mf1, Wp[(1 * 6 + tn) * 64 + l], acc, 0, 0, 0);
      acc = __builtin_amdgcn_mfma_f32_16x16x32_f16(mf2, Wp[(2 * 6 + tn) * 64 + l], acc, 0, 0, 0);
      const int col = tn * 16 + cg;
      const float b = bh2[col];
      #pragma unroll
      for (int r = 0; r < 4; ++r)
        oT[(w * 16 + rg * 4 + r) * 100 + col] = acc[r] + b;
    }
  }
  __syncthreads();
  {
    const int e = tid & 63, q = tid >> 6;
    const int node = nb + e;
    if (node < NN) {
      const float* src = (const float*)inT + e * 100 + q * 24;
      const float* hr = h + (size_t)node * 96 + q * 24;
      float* dst = hout + (size_t)node * 96 + q * 24;
      #pragma unroll
      for (int c = 0; c < 6; ++c) {
        const float4 s = *(const float4*)(src + c * 4);
        const float4 hv = *(const float4*)(hr + c * 4);
        *(float4*)(dst + c * 4) = make_float4(hv.x + s.x, hv.y + s.y, hv.z + s.z, hv.w + s.w);
      }
    }
  }
  if (tid < 64) {
    const int node = nb + tid;
    if (node < NN) {
      const int cnt = basep[node + 1] - basep[node];
      const float inv = cnt > 0 ? 1.f / (float)cnt : 0.f;
      const float4 s4 = *(const float4*)(svm + (long)node * 4);
      const float4 xv = *(const float4*)(x + (long)node * 4);
      *(float4*)(xout + (long)node * 4) =
          make_float4(xv.x + 0.005f * s4.x * inv, xv.y + 0.005f * s4.y * inv,
                      xv.z + 0.005f * s4.z * inv, xv.w + 0.005f * s4.w * inv);
    }
  }
}

// ---------------------------------------------------------------------------
extern "C" void kernel_launch(void* const* d_in, const int* in_sizes, int n_in,
                              void* d_out, int out_size, void* d_ws, size_t ws_size,
                              hipStream_t stream) {
  const float* x   = (const float*)d_in[0];
  const float* h   = (const float*)d_in[1];
  const int*   ei  = (const int*)d_in[2];
  const int*   ej  = (const int*)d_in[3];
  const float* We1 = (const float*)d_in[4];
  const float* be1 = (const float*)d_in[5];
  const float* We2 = (const float*)d_in[6];
  const float* be2 = (const float*)d_in[7];
  const float* Wm  = (const float*)d_in[8];
  const float* bm  = (const float*)d_in[9];
  const float* Wh1 = (const float*)d_in[10];
  const float* bh1 = (const float*)d_in[11];
  const float* Wh2 = (const float*)d_in[12];
  const float* bh2 = (const float*)d_in[13];
  const float* Wx1 = (const float*)d_in[14];
  const float* bx1 = (const float*)d_in[15];
  const float* Wx2 = (const float*)d_in[16];

  char* w = (char*)d_ws;
  unsigned short* Ahf  = (unsigned short*)w;                 //  9.6 MB
  unsigned short* Bhf  = (unsigned short*)(w + 9600000);     //  9.6 MB
  float* WMv  = (float*)(w + 19200000);                      // 19.2 MB
  float* SvM  = (float*)(w + 38400000);                      //  0.8 MB (contiguous after WMv)
  int*   cnt  = (int*)(w + 39200000);                        //  0.2 MB
  int*   base = (int*)(w + 39400000);                        //  0.2 MB (+4)
  int*   curs = (int*)(w + 39600064);                        //  0.2 MB
  unsigned short* We2p = (unsigned short*)(w + 39800064);    // 18 KB
  unsigned short* Wx1p = (unsigned short*)(w + 39818496);    // 18 KB
  unsigned short* We1p = (unsigned short*)(w + 39836928);    // 36 KB
  unsigned short* Wh1p = (unsigned short*)(w + 39873792);    // 36 KB
  unsigned short* Wh2p = (unsigned short*)(w + 39910656);    // 18 KB
  unsigned* WA2 = (unsigned*)(w + 39929088);                 // 192 B
  unsigned* WB2 = (unsigned*)(w + 39929280);                 // 192 B (pad to 39930112)
  int2*  epb  = (int2*)(w + 39930112);                       //  6.4 MB
  int*   pre  = (int*)(w + 46330112);                        //  0.2 MB
  int*   bsum = (int*)(w + 46530112);                        //  784 B

  float* hout = (float*)d_out;
  float* xout = hout + 4800000;

  hipMemsetAsync(cnt, 0, NN * sizeof(int), stream);
  kprep<<<NE / 256 + 72, 256, 0, stream>>>(ei, cnt, We1, We2, Wx1, Wh1, Wh2,
                                           We1p, We2p, Wx1p, Wh1p, Wh2p, WA2, WB2);
  kscanA<<<NB, 256, 0, stream>>>(cnt, pre, bsum);
  kscanBC<<<NB, 256, 0, stream>>>(pre, bsum, base, curs);
  kperm<<<NE / 256, 256, 0, stream>>>(ei, ej, curs, epb, WMv);
  k0_AB<<<782, 256, 0, stream>>>(h, We1p, be1, Ahf, Bhf);
  k1_edge<<<NE / TE, 256, 0, stream>>>(x, Ahf, Bhf, epb, WA2, WB2, We2p, be2,
                                       Wm, bm, Wx1p, bx1, Wx2, WMv, SvM);
  k3ab<<<782, 256, 0, stream>>>(h, WMv, Wh1p, bh1, Wh2p, bh2, x, SvM, base, hout, xout);
}

// Round 19
// 270.481 us; speedup vs baseline: 1.1461x; 1.0047x over previous
//
#include <hip/hip_runtime.h>
#include <math.h>

#define NN 50000
#define NE 800000
#define NB 196   // scan blocks (196*256 >= NN)
#define TE 128   // edges per k1 block

typedef __attribute__((ext_vector_type(8))) _Float16 half8v;
typedef __attribute__((ext_vector_type(2))) _Float16 half2v;
typedef __attribute__((ext_vector_type(4))) float f32x4;

__device__ __forceinline__ unsigned short f2h_us(float f) {
  const _Float16 h = (_Float16)f;
  return *(const unsigned short*)&h;
}
__device__ __forceinline__ unsigned pk2h(float a, float b) {
  half2v h; h[0] = (_Float16)a; h[1] = (_Float16)b;
  return *(unsigned*)&h;
}

// ---------------------------------------------------------------------------
// merged prep: blocks [0,3125) histogram edge_i; blocks [3125,3197) pack weights
__global__ void kprep(const int* __restrict__ ei, int* __restrict__ cnt,
                      const float* __restrict__ We1, const float* __restrict__ We2,
                      const float* __restrict__ Wx1, const float* __restrict__ Wh1,
                      const float* __restrict__ Wh2,
                      unsigned short* __restrict__ We1p, unsigned short* __restrict__ We2p,
                      unsigned short* __restrict__ Wx1p, unsigned short* __restrict__ Wh1p,
                      unsigned short* __restrict__ Wh2p, unsigned* __restrict__ WA2,
                      unsigned* __restrict__ WB2) {
  const int b = blockIdx.x;
  if (b < NE / 256) {
    const int i = b * 256 + threadIdx.x;
    atomicAdd(&cnt[ei[i]], 1);
    return;
  }
  const int t = (b - NE / 256) * 256 + threadIdx.x;   // 0..18431
  const int j = t & 7, lane = (t >> 3) & 63;
  const int kk = (lane >> 4) * 8 + j;
  const int nn = lane & 15;
  {  // We1p: K=96, N=192 (combined [top|bot])
    const int tile = t >> 9, tk = tile / 12, tn = tile % 12;
    const int k = tk * 32 + kk, n2 = tn * 16 + nn;
    const float v = (n2 < 96) ? We1[k * 96 + n2] : We1[(96 + k) * 96 + (n2 - 96)];
    We1p[t] = f2h_us(v);
  }
  {  // Wh1p: K=192, N=96
    const int tile = t >> 9, tk = tile / 6, tn = tile % 6;
    const int k = tk * 32 + kk, n = tn * 16 + nn;
    Wh1p[t] = f2h_us(Wh1[k * 96 + n]);
  }
  if (t < 9216) {  // We2p / Wx1p / Wh2p: K=96, N=96
    const int tile = t >> 9, tk = tile / 6, tn = tile % 6;
    const int k = tk * 32 + kk, n = tn * 16 + nn;
    We2p[t] = f2h_us(We2[k * 96 + n]);
    Wx1p[t] = f2h_us(Wx1[k * 96 + n]);
    Wh2p[t] = f2h_us(Wh2[k * 96 + n]);
  }
  if (t < 48) {  // psi weight rows as half2 pairs
    WA2[t] = pk2h(We1[192 * 96 + 2 * t], We1[192 * 96 + 2 * t + 1]);
    WB2[t] = pk2h(We1[193 * 96 + 2 * t], We1[193 * 96 + 2 * t + 1]);
  }
}

// scan A: per-block local exclusive scan + block sums
__global__ void kscanA(const int* __restrict__ cnt, int* __restrict__ pre,
                       int* __restrict__ bsum) {
  __shared__ int ps[256];
  const int b = blockIdx.x, t = threadIdx.x, idx = b * 256 + t;
  const int v = (idx < NN) ? cnt[idx] : 0;
  ps[t] = v;
  __syncthreads();
  for (int off = 1; off < 256; off <<= 1) {
    const int u = (t >= off) ? ps[t - off] : 0;
    __syncthreads();
    ps[t] += u;
    __syncthreads();
  }
  if (idx < NN) pre[idx] = ps[t] - v;
  if (t == 255) bsum[b] = ps[255];
}

// fused scan B+C: each block recomputes its block-offset from the 196 bsums
__global__ void kscanBC(const int* __restrict__ pre, const int* __restrict__ bsum,
                        int* __restrict__ base, int* __restrict__ cursor) {
  __shared__ int ws[4];
  const int b = blockIdx.x, t = threadIdx.x;
  int s = (t < b) ? bsum[t] : 0;   // b <= 195 < 256
  s += __shfl_xor(s, 1);  s += __shfl_xor(s, 2);  s += __shfl_xor(s, 4);
  s += __shfl_xor(s, 8);  s += __shfl_xor(s, 16); s += __shfl_xor(s, 32);
  if ((t & 63) == 0) ws[t >> 6] = s;
  __syncthreads();
  const int boff = ws[0] + ws[1] + ws[2] + ws[3];
  const int idx = b * 256 + t;
  if (idx < NN) {
    const int v = pre[idx] + boff;
    base[idx] = v;
    cursor[idx] = v;
  }
  if (idx == 0) base[NN] = NE;
}

// sort edges by vi into int2 pairs; also zeroes WMv/SvM (saves a memset dispatch)
__global__ void kperm(const int* __restrict__ ei, const int* __restrict__ ej,
                      int* __restrict__ cursor, int2* __restrict__ ep,
                      float* __restrict__ wz) {
  const int i = blockIdx.x * 256 + threadIdx.x;
  if (i < 625000) {   // 5,000,000 floats = WMv(4.8M) + SvM(0.2M), contiguous
    const float4 z = make_float4(0.f, 0.f, 0.f, 0.f);
    *(float4*)(wz + (size_t)i * 8) = z;
    *(float4*)(wz + (size_t)i * 8 + 4) = z;
  }
  const int vi = ei[i];
  const int pos = atomicAdd(&cursor[vi], 1);
  ep[pos] = make_int2(vi, ej[i]);
}

// ---------------------------------------------------------------------------
// K0 (MFMA f16): [A|B] = h @ [We1_top | We1_bot]; be1 folded into A half.
__global__ __launch_bounds__(256, 4) void k0_AB(const float* __restrict__ h,
                                                const unsigned short* __restrict__ We1p,
                                                const float* __restrict__ be1,
                                                unsigned short* __restrict__ Ahf,
                                                unsigned short* __restrict__ Bhf) {
  __shared__ __align__(16) unsigned short hbT[64 * 104];
  __shared__ __align__(16) unsigned short outT[64 * 200];
  const int tid = threadIdx.x;
  const int nb = blockIdx.x * 64;
  {
    const int e = tid & 63, q = tid >> 6;
    const int node = nb + e;
    const int nc = node < NN ? node : NN - 1;
    const float* hr = h + (long)nc * 96 + q * 24;
    unsigned* dst = (unsigned*)hbT + e * 52 + q * 12;
    #pragma unroll
    for (int c = 0; c < 6; ++c) {
      const float4 v = *(const float4*)(hr + c * 4);
      dst[c * 2]     = pk2h(v.x, v.y);
      dst[c * 2 + 1] = pk2h(v.z, v.w);
    }
  }
  __syncthreads();
  const int l = tid & 63, w = tid >> 6, cg = l & 15, rg = l >> 4;
  {
    const half8v* Wp = (const half8v*)We1p;
    const unsigned short* ar = hbT + (w * 16 + cg) * 104;
    const half8v af0 = *(const half8v*)(ar + rg * 8);
    const half8v af1 = *(const half8v*)(ar + 32 + rg * 8);
    const half8v af2 = *(const half8v*)(ar + 64 + rg * 8);
    #pragma unroll
    for (int tn = 0; tn < 12; ++tn) {
      f32x4 acc = (f32x4){0.f, 0.f, 0.f, 0.f};
      acc = __builtin_amdgcn_mfma_f32_16x16x32_f16(af0, Wp[(0 * 12 + tn) * 64 + l], acc, 0, 0, 0);
      acc = __builtin_amdgcn_mfma_f32_16x16x32_f16(af1, Wp[(1 * 12 + tn) * 64 + l], acc, 0, 0, 0);
      acc = __builtin_amdgcn_mfma_f32_16x16x32_f16(af2, Wp[(2 * 12 + tn) * 64 + l], acc, 0, 0, 0);
      const float bb = (tn < 6) ? be1[tn * 16 + cg] : 0.f;   // fold be1 into A half
      #pragma unroll
      for (int r = 0; r < 4; ++r)
        outT[(w * 16 + rg * 4 + r) * 200 + tn * 16 + cg] = f2h_us(acc[r] + bb);
    }
  }
  __syncthreads();
  {
    const int e = tid & 63, q = tid >> 6;
    const int node = nb + e;
    if (node < NN) {
      const unsigned* src = (const unsigned*)outT + e * 100;
      if (q < 2) {
        uint4* dA = (uint4*)(Ahf + (size_t)node * 96);
        #pragma unroll
        for (int i = 0; i < 6; ++i) dA[q * 6 + i] = *(const uint4*)(src + (q * 6 + i) * 4);
      } else {
        uint4* dB = (uint4*)(Bhf + (size_t)node * 96);
        #pragma unroll
        for (int i = 0; i < 6; ++i) dB[(q - 2) * 6 + i] = *(const uint4*)(src + 48 + ((q - 2) * 6 + i) * 4);
      }
    }
  }
}

// ---------------------------------------------------------------------------
// K1: 128 sorted edges/block (R15 structure); phase-0 in packed fp16 math.
__global__ __launch_bounds__(256, 5) void k1_edge(const float* __restrict__ x,
    const unsigned short* __restrict__ Ahf, const unsigned short* __restrict__ Bhf,
    const int2* __restrict__ ep,
    const unsigned* __restrict__ WA2, const unsigned* __restrict__ WB2,
    const unsigned short* __restrict__ We2p, const float* __restrict__ be2,
    const float* __restrict__ Wm, const float* __restrict__ bm,
    const unsigned short* __restrict__ Wx1p, const float* __restrict__ bx1,
    const float* __restrict__ Wx2,
    float* __restrict__ wmo, float* __restrict__ svo) {
  __shared__ __align__(16) unsigned short actT[TE * 104];
  __shared__ float gl[TE];
  __shared__ float phil[TE];
  __shared__ __align__(16) float xjl[TE * 4];
  __shared__ int vseq[TE + 2];
  __shared__ unsigned long long bmask[2];

  const int tid = threadIdx.x;
  const float bm0 = bm[0];
  const int tb = blockIdx.x * TE;

  // ---- phase 0: gather + h1 (packed fp16; thread: edge e2, feature half hf)
  {
    const int e2 = tid & 127, hf = tid >> 7;
    const int fb = hf * 48;
    const int2 v2 = ep[tb + e2];
    const int vi = v2.x, vj = v2.y;
    const float4 xi = *(const float4*)(x + (long)vi * 4);
    const float4 xj = *(const float4*)(x + (long)vj * 4);
    if (hf == 0) {
      vseq[1 + e2] = vi;
      *(float4*)(xjl + e2 * 4) = xj;
    }
    if (tid == 0) {
      vseq[0] = (tb > 0) ? ep[tb - 1].x : -1;
      vseq[TE + 1] = (tb + TE < NE) ? ep[tb + TE].x : -1;
    }
    const float d0 = xi.x - xj.x, d1 = xi.y - xj.y, d2 = xi.z - xj.z, d3 = xi.w - xj.w;
    const float nrm = d0 * d0 - d1 * d1 - d2 * d2 - d3 * d3;
    const float prd = xi.x * xj.x - xi.y * xj.y - xi.z * xj.z - xi.w * xj.w;
    const float pn = copysignf(logf(fabsf(nrm) + 1.f), nrm);
    const float pp = copysignf(logf(fabsf(prd) + 1.f), prd);
    half2v pn2; pn2[0] = (_Float16)pn; pn2[1] = (_Float16)pn;
    half2v pp2; pp2[0] = (_Float16)pp; pp2[1] = (_Float16)pp;
    const half2v z2 = (half2v){(_Float16)0.f, (_Float16)0.f};
    const uint4* Ar = (const uint4*)(Ahf + (size_t)vi * 96 + fb);
    const uint4* Br = (const uint4*)(Bhf + (size_t)vj * 96 + fb);
    const half2v* wa2 = (const half2v*)(WA2 + fb / 2);
    const half2v* wb2 = (const half2v*)(WB2 + fb / 2);
    unsigned* arow = (unsigned*)actT + e2 * 52 + hf * 24;
    #pragma unroll
    for (int c = 0; c < 6; ++c) {
      const uint4 A4 = Ar[c], B4 = Br[c];
      const half2v* a2 = (const half2v*)&A4;
      const half2v* b2 = (const half2v*)&B4;
      #pragma unroll
      for (int k2 = 0; k2 < 4; ++k2) {
        half2v t = a2[k2] + b2[k2];
        t = pn2 * wa2[c * 4 + k2] + t;
        t = pp2 * wb2[c * 4 + k2] + t;
        t = __builtin_elementwise_max(t, z2);
        arow[c * 4 + k2] = *(unsigned*)&t;
      }
    }
  }
  __syncthreads();

  // ---- run-end boundary mask via ballot (waves 0,1)
  if (tid < TE) {
    const int pred = (vseq[1 + tid] != vseq[2 + tid]) ? 1 : 0;
    const unsigned long long mk = __ballot(pred);
    if ((tid & 63) == 0) bmask[tid >> 6] = mk;
  }

  const int l = tid & 63, w = tid >> 6;
  const int cg = l & 15, rg = l >> 4;
  const int r0 = w * 32;
  const half8v* Wp2 = (const half8v*)We2p;
  const half8v* Wpx = (const half8v*)Wx1p;

  // ---- GEMM2: m = relu(h1 @ We2 + be2); gate
  {
    half8v af[2][3];
    #pragma unroll
    for (int rt = 0; rt < 2; ++rt)
      #pragma unroll
      for (int tk = 0; tk < 3; ++tk)
        af[rt][tk] = *(const half8v*)(actT + (r0 + rt * 16 + cg) * 104 + tk * 32 + rg * 8);
    f32x4 acc[2][6];
    #pragma unroll
    for (int rt = 0; rt < 2; ++rt)
      #pragma unroll
      for (int tn = 0; tn < 6; ++tn) acc[rt][tn] = (f32x4){0.f, 0.f, 0.f, 0.f};
    #pragma unroll
    for (int tk = 0; tk < 3; ++tk)
      #pragma unroll
      for (int tn = 0; tn < 6; ++tn) {
        const half8v bf = Wp2[(tk * 6 + tn) * 64 + l];
        acc[0][tn] = __builtin_amdgcn_mfma_f32_16x16x32_f16(af[0][tk], bf, acc[0][tn], 0, 0, 0);
        acc[1][tn] = __builtin_amdgcn_mfma_f32_16x16x32_f16(af[1][tk], bf, acc[1][tn], 0, 0, 0);
      }
    #pragma unroll
    for (int rt = 0; rt < 2; ++rt) {
      float gp[4] = {0.f, 0.f, 0.f, 0.f};
      #pragma unroll
      for (int tn = 0; tn < 6; ++tn) {
        const int col = tn * 16 + cg;
        const float b = be2[col], wmw = Wm[col];
        #pragma unroll
        for (int r = 0; r < 4; ++r) {
          const float v = fmaxf(acc[rt][tn][r] + b, 0.f);
          gp[r] = fmaf(v, wmw, gp[r]);
          actT[(r0 + rt * 16 + rg * 4 + r) * 104 + col] = f2h_us(v);
        }
      }
      #pragma unroll
      for (int r = 0; r < 4; ++r) {
        float s = gp[r];
        s += __shfl_xor(s, 1); s += __shfl_xor(s, 2);
        s += __shfl_xor(s, 4); s += __shfl_xor(s, 8);
        if (cg == 0) gl[r0 + rt * 16 + rg * 4 + r] = 1.f / (1.f + expf(-(s + bm0)));
      }
    }
  }

  // no barrier: each wave reads only its own rows (m written by itself)

  // ---- GEMM3: phi = relu(m @ Wx1 + bx1) . Wx2
  {
    half8v af[2][3];
    #pragma unroll
    for (int rt = 0; rt < 2; ++rt)
      #pragma unroll
      for (int tk = 0; tk < 3; ++tk)
        af[rt][tk] = *(const half8v*)(actT + (r0 + rt * 16 + cg) * 104 + tk * 32 + rg * 8);
    f32x4 acc[2][6];
    #pragma unroll
    for (int rt = 0; rt < 2; ++rt)
      #pragma unroll
      for (int tn = 0; tn < 6; ++tn) acc[rt][tn] = (f32x4){0.f, 0.f, 0.f, 0.f};
    #pragma unroll
    for (int tk = 0; tk < 3; ++tk)
      #pragma unroll
      for (int tn = 0; tn < 6; ++tn) {
        const half8v bf = Wpx[(tk * 6 + tn) * 64 + l];
        acc[0][tn] = __builtin_amdgcn_mfma_f32_16x16x32_f16(af[0][tk], bf, acc[0][tn], 0, 0, 0);
        acc[1][tn] = __builtin_amdgcn_mfma_f32_16x16x32_f16(af[1][tk], bf, acc[1][tn], 0, 0, 0);
      }
    #pragma unroll
    for (int rt = 0; rt < 2; ++rt) {
      float pp2[4] = {0.f, 0.f, 0.f, 0.f};
      #pragma unroll
      for (int tn = 0; tn < 6; ++tn) {
        const int col = tn * 16 + cg;
        const float b = bx1[col], wxw = Wx2[col];
        #pragma unroll
        for (int r = 0; r < 4; ++r)
          pp2[r] = fmaf(fmaxf(acc[rt][tn][r] + b, 0.f), wxw, pp2[r]);
      }
      #pragma unroll
      for (int r = 0; r < 4; ++r) {
        float s = pp2[r];
        s += __shfl_xor(s, 1); s += __shfl_xor(s, 2);
        s += __shfl_xor(s, 4); s += __shfl_xor(s, 8);
        if (cg == 0) phil[r0 + rt * 16 + rg * 4 + r] = s;
      }
    }
  }
  __syncthreads();

  // ---- fused segmented reduction: 48 col-pairs x 4 quarters, b32 reads
  if (tid < 192) {
    const int p = tid % 48;          // column pair: cols 2p, 2p+1
    const int q = tid / 48;          // quarter: edges [q*32, q*32+32)
    const int s_lo = q * 32;
    const unsigned long long mk = bmask[s_lo >> 6];
    float a0 = 0.f, a1 = 0.f;
    bool clean = (q == 0) ? (vseq[0] != vseq[1])
                          : (((bmask[(s_lo - 1) >> 6] >> ((s_lo - 1) & 63)) & 1ull) != 0);
    for (int i = 0; i < 32; ++i) {
      const int e = s_lo + i;
      const half2v h2 = *(const half2v*)(actT + e * 104 + 2 * p);
      const float g = gl[e];
      a0 = fmaf(g, (float)h2[0], a0);
      a1 = fmaf(g, (float)h2[1], a1);
      const bool gend = ((mk >> (e & 63)) & 1ull) != 0;
      if (gend || i == 31) {
        const int node = vseq[e + 1];
        float* dst = wmo + (size_t)node * 96 + 2 * p;
        if (clean && gend) {
          *(float2*)dst = make_float2(a0, a1);
        } else {
          atomicAdd(dst, a0);
          atomicAdd(dst + 1, a1);
        }
        a0 = a1 = 0.f; clean = true;
      }
    }
  } else if (tid < 224) {
    // x-part: 4 comps x 8 sixteenths(16 edges)
    const int t2 = tid - 192;
    const int comp = t2 & 3, q8 = t2 >> 2;
    const int s_lo = q8 * 16;
    const unsigned long long mk = bmask[s_lo >> 6];
    float acc2 = 0.f;
    bool clean = (q8 == 0) ? (vseq[0] != vseq[1])
                           : (((bmask[(s_lo - 1) >> 6] >> ((s_lo - 1) & 63)) & 1ull) != 0);
    for (int i = 0; i < 16; ++i) {
      const int e = s_lo + i;
      acc2 = fmaf(phil[e], xjl[e * 4 + comp], acc2);
      const bool gend = ((mk >> (e & 63)) & 1ull) != 0;
      if (gend || i == 15) {
        const int node = vseq[e + 1];
        float* dst = svo + (size_t)node * 4 + comp;
        if (clean && gend) *dst = acc2; else atomicAdd(dst, acc2);
        acc2 = 0.f; clean = true;
      }
    }
  }
}

// ---------------------------------------------------------------------------
// K3 fused (MFMA f16), wave-local staging: only ONE barrier.
// Lane l of wave w stages row w*16+(l&15), col-group l>>4 -> inT wave-local.
__global__ __launch_bounds__(256, 4) void k3ab(const float* __restrict__ h,
    const float* __restrict__ wmv,
    const unsigned short* __restrict__ Wh1p, const float* __restrict__ bh1,
    const unsigned short* __restrict__ Wh2p, const float* __restrict__ bh2,
    const float* __restrict__ x, const float* __restrict__ svm,
    const int* __restrict__ basep,
    float* __restrict__ hout, float* __restrict__ xout) {
  __shared__ __align__(16) unsigned short inT[64 * 200];   // reused as float[64][100]
  __shared__ __align__(16) unsigned short tmpT[64 * 104];
  const int tid = threadIdx.x;
  const int nb = blockIdx.x * 64;
  const int l = tid & 63, w = tid >> 6, cg = l & 15, rg = l >> 4;
  {
    // wave-local staging: row r = w*16 + (l&15), col-group cg2 = l>>4 (24 cols)
    const int r = w * 16 + (l & 15);
    const int cg2 = l >> 4;
    const int node = nb + r;
    const int nc = node < NN ? node : NN - 1;
    const float* hr = h + (long)nc * 96 + cg2 * 24;
    const float* wr = wmv + (long)nc * 96 + cg2 * 24;
    unsigned* dh = (unsigned*)inT + r * 100 + cg2 * 12;
    unsigned* dw = (unsigned*)inT + r * 100 + 48 + cg2 * 12;
    #pragma unroll
    for (int c = 0; c < 6; ++c) {
      const float4 v = *(const float4*)(hr + c * 4);
      dh[c * 2]     = pk2h(v.x, v.y);
      dh[c * 2 + 1] = pk2h(v.z, v.w);
      const float4 u = *(const float4*)(wr + c * 4);
      dw[c * 2]     = pk2h(u.x, u.y);
      dw[c * 2 + 1] = pk2h(u.z, u.w);
    }
  }
  // no barrier: inT rows w*16..w*16+15 fully staged by wave w itself
  {
    const unsigned short* ar = inT + (w * 16 + cg) * 200;
    half8v af[6];
    #pragma unroll
    for (int tk = 0; tk < 6; ++tk) af[tk] = *(const half8v*)(ar + tk * 32 + rg * 8);
    const half8v* Wp = (const half8v*)Wh1p;
    #pragma unroll
    for (int tn = 0; tn < 6; ++tn) {
      f32x4 acc = (f32x4){0.f, 0.f, 0.f, 0.f};
      #pragma unroll
      for (int tk = 0; tk < 6; ++tk)
        acc = __builtin_amdgcn_mfma_f32_16x16x32_f16(af[tk], Wp[(tk * 6 + tn) * 64 + l], acc, 0, 0, 0);
      const int col = tn * 16 + cg;
      const float b = bh1[col];
      #pragma unroll
      for (int r = 0; r < 4; ++r)
        tmpT[(w * 16 + rg * 4 + r) * 104 + col] = f2h_us(fmaxf(acc[r] + b, 0.f));
    }
  }
  // no barrier: tmpT rows wave-local
  {
    float* oT = (float*)inT;
    const unsigned short* mr = tmpT + (w * 16 + cg) * 104;
    const half8v mf0 = *(const half8v*)(mr + rg * 8);
    const half8v mf1 = *(const half8v*)(mr + 32 + rg * 8);
    const half8v mf2 = *(const half8v*)(mr + 64 + rg * 8);
    const half8v* Wp = (const half8v*)Wh2p;
    #pragma unroll
    for (int tn = 0; tn < 6; ++tn) {
      f32x4 acc = (f32x4){0.f, 0.f, 0.f, 0.f};
      acc = __builtin_amdgcn_mfma_f32_16x16x32_f16(mf0, Wp[(0 * 6 + tn) * 64 + l], acc, 0, 0, 0);
      acc = __builtin_amdgcn_mfma_f32_16x16x32_f16(mf1, Wp[(1 * 6 + tn) * 64 + l], acc, 0, 0, 0);
      acc = __builtin_amdgcn_mfma_f32_16x16x32_f16(mf2, Wp[(2 * 6 + tn) * 64 + l], acc, 0, 0, 0);
      const int col = tn * 16 + cg;
      const float b = bh2[col];
      #pragma unroll
      for (int r = 0; r < 4; ++r)
        oT[(w * 16 + rg * 4 + r) * 100 + col] = acc[r] + b;
    }
  }
  __syncthreads();
  {
    const int e = tid & 63, q = tid >> 6;
    const int node = nb + e;
    if (node < NN) {
      const float* src = (const float*)inT + e * 100 + q * 24;
      const float* hr = h + (size_t)node * 96 + q * 24;
      float* dst = hout + (size_t)node * 96 + q * 24;
      #pragma unroll
      for (int c = 0; c < 6; ++c) {
        const float4 s = *(const float4*)(src + c * 4);
        const float4 hv = *(const float4*)(hr + c * 4);
        *(float4*)(dst + c * 4) = make_float4(hv.x + s.x, hv.y + s.y, hv.z + s.z, hv.w + s.w);
      }
    }
  }
  if (tid < 64) {
    const int node = nb + tid;
    if (node < NN) {
      const int cnt = basep[node + 1] - basep[node];
      const float inv = cnt > 0 ? 1.f / (float)cnt : 0.f;
      const float4 s4 = *(const float4*)(svm + (long)node * 4);
      const float4 xv = *(const float4*)(x + (long)node * 4);
      *(float4*)(xout + (long)node * 4) =
          make_float4(xv.x + 0.005f * s4.x * inv, xv.y + 0.005f * s4.y * inv,
                      xv.z + 0.005f * s4.z * inv, xv.w + 0.005f * s4.w * inv);
    }
  }
}

// ---------------------------------------------------------------------------
extern "C" void kernel_launch(void* const* d_in, const int* in_sizes, int n_in,
                              void* d_out, int out_size, void* d_ws, size_t ws_size,
                              hipStream_t stream) {
  const float* x   = (const float*)d_in[0];
  const float* h   = (const float*)d_in[1];
  const int*   ei  = (const int*)d_in[2];
  const int*   ej  = (const int*)d_in[3];
  const float* We1 = (const float*)d_in[4];
  const float* be1 = (const float*)d_in[5];
  const float* We2 = (const float*)d_in[6];
  const float* be2 = (const float*)d_in[7];
  const float* Wm  = (const float*)d_in[8];
  const float* bm  = (const float*)d_in[9];
  const float* Wh1 = (const float*)d_in[10];
  const float* bh1 = (const float*)d_in[11];
  const float* Wh2 = (const float*)d_in[12];
  const float* bh2 = (const float*)d_in[13];
  const float* Wx1 = (const float*)d_in[14];
  const float* bx1 = (const float*)d_in[15];
  const float* Wx2 = (const float*)d_in[16];

  char* w = (char*)d_ws;
  unsigned short* Ahf  = (unsigned short*)w;                 //  9.6 MB
  unsigned short* Bhf  = (unsigned short*)(w + 9600000);     //  9.6 MB
  float* WMv  = (float*)(w + 19200000);                      // 19.2 MB
  float* SvM  = (float*)(w + 38400000);                      //  0.8 MB (contiguous after WMv)
  int*   cnt  = (int*)(w + 39200000);                        //  0.2 MB
  int*   base = (int*)(w + 39400000);                        //  0.2 MB (+4)
  int*   curs = (int*)(w + 39600064);                        //  0.2 MB
  unsigned short* We2p = (unsigned short*)(w + 39800064);    // 18 KB
  unsigned short* Wx1p = (unsigned short*)(w + 39818496);    // 18 KB
  unsigned short* We1p = (unsigned short*)(w + 39836928);    // 36 KB
  unsigned short* Wh1p = (unsigned short*)(w + 39873792);    // 36 KB
  unsigned short* Wh2p = (unsigned short*)(w + 39910656);    // 18 KB
  unsigned* WA2 = (unsigned*)(w + 39929088);                 // 192 B
  unsigned* WB2 = (unsigned*)(w + 39929280);                 // 192 B (pad to 39930112)
  int2*  epb  = (int2*)(w + 39930112);                       //  6.4 MB
  int*   pre  = (int*)(w + 46330112);                        //  0.2 MB
  int*   bsum = (int*)(w + 46530112);                        //  784 B

  float* hout = (float*)d_out;
  float* xout = hout + 4800000;

  hipMemsetAsync(cnt, 0, NN * sizeof(int), stream);
  kprep<<<NE / 256 + 72, 256, 0, stream>>>(ei, cnt, We1, We2, Wx1, Wh1, Wh2,
                                           We1p, We2p, Wx1p, Wh1p, Wh2p, WA2, WB2);
  kscanA<<<NB, 256, 0, stream>>>(cnt, pre, bsum);
  kscanBC<<<NB, 256, 0, stream>>>(pre, bsum, base, curs);
  kperm<<<NE / 256, 256, 0, stream>>>(ei, ej, curs, epb, WMv);
  k0_AB<<<782, 256, 0, stream>>>(h, We1p, be1, Ahf, Bhf);
  k1_edge<<<NE / TE, 256, 0, stream>>>(x, Ahf, Bhf, epb, WA2, WB2, We2p, be2,
                                       Wm, bm, Wx1p, bx1, Wx2, WMv, SvM);
  k3ab<<<782, 256, 0, stream>>>(h, WMv, Wh1p, bh1, Wh2p, bh2, x, SvM, base, hout, xout);
}

// Round 20
// 260.255 us; speedup vs baseline: 1.1912x; 1.0393x over previous
//
#include <hip/hip_runtime.h>
#include <math.h>

#define NN 50000
#define NE 800000
#define NB 196   // scan blocks (196*256 >= NN)
#define TE 128   // edges per k1 block

typedef __attribute__((ext_vector_type(8))) _Float16 half8v;
typedef __attribute__((ext_vector_type(2))) _Float16 half2v;
typedef __attribute__((ext_vector_type(4))) float f32x4;

__device__ __forceinline__ unsigned short f2h_us(float f) {
  const _Float16 h = (_Float16)f;
  return *(const unsigned short*)&h;
}
__device__ __forceinline__ unsigned pk2h(float a, float b) {
  half2v h; h[0] = (_Float16)a; h[1] = (_Float16)b;
  return *(unsigned*)&h;
}

// ---------------------------------------------------------------------------
// merged prep: blocks [0,3125) histogram edge_i; blocks [3125,3197) pack weights
__global__ void kprep(const int* __restrict__ ei, int* __restrict__ cnt,
                      const float* __restrict__ We1, const float* __restrict__ We2,
                      const float* __restrict__ Wx1, const float* __restrict__ Wh1,
                      const float* __restrict__ Wh2,
                      unsigned short* __restrict__ We1p, unsigned short* __restrict__ We2p,
                      unsigned short* __restrict__ Wx1p, unsigned short* __restrict__ Wh1p,
                      unsigned short* __restrict__ Wh2p, unsigned* __restrict__ WA2,
                      unsigned* __restrict__ WB2) {
  const int b = blockIdx.x;
  if (b < NE / 256) {
    const int i = b * 256 + threadIdx.x;
    atomicAdd(&cnt[ei[i]], 1);
    return;
  }
  const int t = (b - NE / 256) * 256 + threadIdx.x;   // 0..18431
  const int j = t & 7, lane = (t >> 3) & 63;
  const int kk = (lane >> 4) * 8 + j;
  const int nn = lane & 15;
  {  // We1p: K=96, N=192 (combined [top|bot])
    const int tile = t >> 9, tk = tile / 12, tn = tile % 12;
    const int k = tk * 32 + kk, n2 = tn * 16 + nn;
    const float v = (n2 < 96) ? We1[k * 96 + n2] : We1[(96 + k) * 96 + (n2 - 96)];
    We1p[t] = f2h_us(v);
  }
  {  // Wh1p: K=192, N=96
    const int tile = t >> 9, tk = tile / 6, tn = tile % 6;
    const int k = tk * 32 + kk, n = tn * 16 + nn;
    Wh1p[t] = f2h_us(Wh1[k * 96 + n]);
  }
  if (t < 9216) {  // We2p / Wx1p / Wh2p: K=96, N=96
    const int tile = t >> 9, tk = tile / 6, tn = tile % 6;
    const int k = tk * 32 + kk, n = tn * 16 + nn;
    We2p[t] = f2h_us(We2[k * 96 + n]);
    Wx1p[t] = f2h_us(Wx1[k * 96 + n]);
    Wh2p[t] = f2h_us(Wh2[k * 96 + n]);
  }
  if (t < 48) {  // psi weight rows as half2 pairs
    WA2[t] = pk2h(We1[192 * 96 + 2 * t], We1[192 * 96 + 2 * t + 1]);
    WB2[t] = pk2h(We1[193 * 96 + 2 * t], We1[193 * 96 + 2 * t + 1]);
  }
}

// scan A: per-block local exclusive scan + block sums
__global__ void kscanA(const int* __restrict__ cnt, int* __restrict__ pre,
                       int* __restrict__ bsum) {
  __shared__ int ps[256];
  const int b = blockIdx.x, t = threadIdx.x, idx = b * 256 + t;
  const int v = (idx < NN) ? cnt[idx] : 0;
  ps[t] = v;
  __syncthreads();
  for (int off = 1; off < 256; off <<= 1) {
    const int u = (t >= off) ? ps[t - off] : 0;
    __syncthreads();
    ps[t] += u;
    __syncthreads();
  }
  if (idx < NN) pre[idx] = ps[t] - v;
  if (t == 255) bsum[b] = ps[255];
}

// fused scan B+C: each block recomputes its block-offset from the 196 bsums
__global__ void kscanBC(const int* __restrict__ pre, const int* __restrict__ bsum,
                        int* __restrict__ base, int* __restrict__ cursor) {
  __shared__ int ws[4];
  const int b = blockIdx.x, t = threadIdx.x;
  int s = (t < b) ? bsum[t] : 0;   // b <= 195 < 256
  s += __shfl_xor(s, 1);  s += __shfl_xor(s, 2);  s += __shfl_xor(s, 4);
  s += __shfl_xor(s, 8);  s += __shfl_xor(s, 16); s += __shfl_xor(s, 32);
  if ((t & 63) == 0) ws[t >> 6] = s;
  __syncthreads();
  const int boff = ws[0] + ws[1] + ws[2] + ws[3];
  const int idx = b * 256 + t;
  if (idx < NN) {
    const int v = pre[idx] + boff;
    base[idx] = v;
    cursor[idx] = v;
  }
  if (idx == 0) base[NN] = NE;
}

// sort edges by vi into int2 pairs; also zeroes WMv/SvM (saves a memset dispatch)
__global__ void kperm(const int* __restrict__ ei, const int* __restrict__ ej,
                      int* __restrict__ cursor, int2* __restrict__ ep,
                      float* __restrict__ wz) {
  const int i = blockIdx.x * 256 + threadIdx.x;
  if (i < 625000) {   // 5,000,000 floats = WMv(4.8M) + SvM(0.2M), contiguous
    const float4 z = make_float4(0.f, 0.f, 0.f, 0.f);
    *(float4*)(wz + (size_t)i * 8) = z;
    *(float4*)(wz + (size_t)i * 8 + 4) = z;
  }
  const int vi = ei[i];
  const int pos = atomicAdd(&cursor[vi], 1);
  ep[pos] = make_int2(vi, ej[i]);
}

// ---------------------------------------------------------------------------
// K0 (MFMA f16): [A|B] = h @ [We1_top | We1_bot]; be1 folded into A half.
__global__ __launch_bounds__(256, 4) void k0_AB(const float* __restrict__ h,
                                                const unsigned short* __restrict__ We1p,
                                                const float* __restrict__ be1,
                                                unsigned short* __restrict__ Ahf,
                                                unsigned short* __restrict__ Bhf) {
  __shared__ __align__(16) unsigned short hbT[64 * 104];
  __shared__ __align__(16) unsigned short outT[64 * 200];
  const int tid = threadIdx.x;
  const int nb = blockIdx.x * 64;
  {
    const int e = tid & 63, q = tid >> 6;
    const int node = nb + e;
    const int nc = node < NN ? node : NN - 1;
    const float* hr = h + (long)nc * 96 + q * 24;
    unsigned* dst = (unsigned*)hbT + e * 52 + q * 12;
    #pragma unroll
    for (int c = 0; c < 6; ++c) {
      const float4 v = *(const float4*)(hr + c * 4);
      dst[c * 2]     = pk2h(v.x, v.y);
      dst[c * 2 + 1] = pk2h(v.z, v.w);
    }
  }
  __syncthreads();
  const int l = tid & 63, w = tid >> 6, cg = l & 15, rg = l >> 4;
  {
    const half8v* Wp = (const half8v*)We1p;
    const unsigned short* ar = hbT + (w * 16 + cg) * 104;
    const half8v af0 = *(const half8v*)(ar + rg * 8);
    const half8v af1 = *(const half8v*)(ar + 32 + rg * 8);
    const half8v af2 = *(const half8v*)(ar + 64 + rg * 8);
    #pragma unroll
    for (int tn = 0; tn < 12; ++tn) {
      f32x4 acc = (f32x4){0.f, 0.f, 0.f, 0.f};
      acc = __builtin_amdgcn_mfma_f32_16x16x32_f16(af0, Wp[(0 * 12 + tn) * 64 + l], acc, 0, 0, 0);
      acc = __builtin_amdgcn_mfma_f32_16x16x32_f16(af1, Wp[(1 * 12 + tn) * 64 + l], acc, 0, 0, 0);
      acc = __builtin_amdgcn_mfma_f32_16x16x32_f16(af2, Wp[(2 * 12 + tn) * 64 + l], acc, 0, 0, 0);
      const float bb = (tn < 6) ? be1[tn * 16 + cg] : 0.f;   // fold be1 into A half
      #pragma unroll
      for (int r = 0; r < 4; ++r)
        outT[(w * 16 + rg * 4 + r) * 200 + tn * 16 + cg] = f2h_us(acc[r] + bb);
    }
  }
  __syncthreads();
  {
    const int e = tid & 63, q = tid >> 6;
    const int node = nb + e;
    if (node < NN) {
      const unsigned* src = (const unsigned*)outT + e * 100;
      if (q < 2) {
        uint4* dA = (uint4*)(Ahf + (size_t)node * 96);
        #pragma unroll
        for (int i = 0; i < 6; ++i) dA[q * 6 + i] = *(const uint4*)(src + (q * 6 + i) * 4);
      } else {
        uint4* dB = (uint4*)(Bhf + (size_t)node * 96);
        #pragma unroll
        for (int i = 0; i < 6; ++i) dB[(q - 2) * 6 + i] = *(const uint4*)(src + 48 + ((q - 2) * 6 + i) * 4);
      }
    }
  }
}

// ---------------------------------------------------------------------------
// K1: 128 sorted edges/block, 512 threads (8 waves x 1 row-tile).
// Halved per-wave chains + 75% occupancy target.
__global__ __launch_bounds__(512, 6) void k1_edge(const float* __restrict__ x,
    const unsigned short* __restrict__ Ahf, const unsigned short* __restrict__ Bhf,
    const int2* __restrict__ ep,
    const unsigned* __restrict__ WA2, const unsigned* __restrict__ WB2,
    const unsigned short* __restrict__ We2p, const float* __restrict__ be2,
    const float* __restrict__ Wm, const float* __restrict__ bm,
    const unsigned short* __restrict__ Wx1p, const float* __restrict__ bx1,
    const float* __restrict__ Wx2,
    float* __restrict__ wmo, float* __restrict__ svo) {
  __shared__ __align__(16) unsigned short actT[TE * 104];
  __shared__ float gl[TE];
  __shared__ float phil[TE];
  __shared__ __align__(16) float xjl[TE * 4];
  __shared__ int vseq[TE + 2];
  __shared__ unsigned long long bmask[2];

  const int tid = threadIdx.x;
  const float bm0 = bm[0];
  const int tb = blockIdx.x * TE;

  // ---- phase 0: gather + h1 (packed fp16; thread: edge e2, feature quarter qf)
  {
    const int e2 = tid & 127, qf = tid >> 7;     // qf in [0,4): 24 features each
    const int fb = qf * 24;
    const int2 v2 = ep[tb + e2];
    const int vi = v2.x, vj = v2.y;
    const float4 xi = *(const float4*)(x + (long)vi * 4);
    const float4 xj = *(const float4*)(x + (long)vj * 4);
    if (qf == 0) {
      vseq[1 + e2] = vi;
      *(float4*)(xjl + e2 * 4) = xj;
    }
    if (tid == 0) {
      vseq[0] = (tb > 0) ? ep[tb - 1].x : -1;
      vseq[TE + 1] = (tb + TE < NE) ? ep[tb + TE].x : -1;
    }
    const float d0 = xi.x - xj.x, d1 = xi.y - xj.y, d2 = xi.z - xj.z, d3 = xi.w - xj.w;
    const float nrm = d0 * d0 - d1 * d1 - d2 * d2 - d3 * d3;
    const float prd = xi.x * xj.x - xi.y * xj.y - xi.z * xj.z - xi.w * xj.w;
    const float pn = copysignf(logf(fabsf(nrm) + 1.f), nrm);
    const float pp = copysignf(logf(fabsf(prd) + 1.f), prd);
    half2v pn2; pn2[0] = (_Float16)pn; pn2[1] = (_Float16)pn;
    half2v pp2; pp2[0] = (_Float16)pp; pp2[1] = (_Float16)pp;
    const half2v z2 = (half2v){(_Float16)0.f, (_Float16)0.f};
    const uint4* Ar = (const uint4*)(Ahf + (size_t)vi * 96 + fb);
    const uint4* Br = (const uint4*)(Bhf + (size_t)vj * 96 + fb);
    const half2v* wa2 = (const half2v*)(WA2 + fb / 2);
    const half2v* wb2 = (const half2v*)(WB2 + fb / 2);
    unsigned* arow = (unsigned*)actT + e2 * 52 + qf * 12;
    #pragma unroll
    for (int c = 0; c < 3; ++c) {
      const uint4 A4 = Ar[c], B4 = Br[c];
      const half2v* a2 = (const half2v*)&A4;
      const half2v* b2 = (const half2v*)&B4;
      #pragma unroll
      for (int k2 = 0; k2 < 4; ++k2) {
        half2v t = a2[k2] + b2[k2];
        t = pn2 * wa2[c * 4 + k2] + t;
        t = pp2 * wb2[c * 4 + k2] + t;
        t = __builtin_elementwise_max(t, z2);
        arow[c * 4 + k2] = *(unsigned*)&t;
      }
    }
  }
  __syncthreads();

  // ---- run-end boundary mask via ballot (waves 0,1)
  if (tid < TE) {
    const int pred = (vseq[1 + tid] != vseq[2 + tid]) ? 1 : 0;
    const unsigned long long mk = __ballot(pred);
    if ((tid & 63) == 0) bmask[tid >> 6] = mk;
  }

  const int l = tid & 63, w = tid >> 6;   // w in [0,8)
  const int cg = l & 15, rg = l >> 4;
  const int r0 = w * 16;                   // 1 row-tile per wave
  const half8v* Wp2 = (const half8v*)We2p;
  const half8v* Wpx = (const half8v*)Wx1p;

  // ---- GEMM2: m = relu(h1 @ We2 + be2); gate
  {
    half8v af[3];
    #pragma unroll
    for (int tk = 0; tk < 3; ++tk)
      af[tk] = *(const half8v*)(actT + (r0 + cg) * 104 + tk * 32 + rg * 8);
    f32x4 acc[6];
    #pragma unroll
    for (int tn = 0; tn < 6; ++tn) acc[tn] = (f32x4){0.f, 0.f, 0.f, 0.f};
    #pragma unroll
    for (int tk = 0; tk < 3; ++tk)
      #pragma unroll
      for (int tn = 0; tn < 6; ++tn)
        acc[tn] = __builtin_amdgcn_mfma_f32_16x16x32_f16(af[tk], Wp2[(tk * 6 + tn) * 64 + l], acc[tn], 0, 0, 0);
    float gp[4] = {0.f, 0.f, 0.f, 0.f};
    #pragma unroll
    for (int tn = 0; tn < 6; ++tn) {
      const int col = tn * 16 + cg;
      const float b = be2[col], wmw = Wm[col];
      #pragma unroll
      for (int r = 0; r < 4; ++r) {
        const float v = fmaxf(acc[tn][r] + b, 0.f);
        gp[r] = fmaf(v, wmw, gp[r]);
        actT[(r0 + rg * 4 + r) * 104 + col] = f2h_us(v);
      }
    }
    #pragma unroll
    for (int r = 0; r < 4; ++r) {
      float s = gp[r];
      s += __shfl_xor(s, 1); s += __shfl_xor(s, 2);
      s += __shfl_xor(s, 4); s += __shfl_xor(s, 8);
      if (cg == 0) gl[r0 + rg * 4 + r] = 1.f / (1.f + expf(-(s + bm0)));
    }
  }

  // no barrier: each wave reads only its own rows (m written by itself)

  // ---- GEMM3: phi = relu(m @ Wx1 + bx1) . Wx2
  {
    half8v af[3];
    #pragma unroll
    for (int tk = 0; tk < 3; ++tk)
      af[tk] = *(const half8v*)(actT + (r0 + cg) * 104 + tk * 32 + rg * 8);
    f32x4 acc[6];
    #pragma unroll
    for (int tn = 0; tn < 6; ++tn) acc[tn] = (f32x4){0.f, 0.f, 0.f, 0.f};
    #pragma unroll
    for (int tk = 0; tk < 3; ++tk)
      #pragma unroll
      for (int tn = 0; tn < 6; ++tn)
        acc[tn] = __builtin_amdgcn_mfma_f32_16x16x32_f16(af[tk], Wpx[(tk * 6 + tn) * 64 + l], acc[tn], 0, 0, 0);
    float pq[4] = {0.f, 0.f, 0.f, 0.f};
    #pragma unroll
    for (int tn = 0; tn < 6; ++tn) {
      const int col = tn * 16 + cg;
      const float b = bx1[col], wxw = Wx2[col];
      #pragma unroll
      for (int r = 0; r < 4; ++r)
        pq[r] = fmaf(fmaxf(acc[tn][r] + b, 0.f), wxw, pq[r]);
    }
    #pragma unroll
    for (int r = 0; r < 4; ++r) {
      float s = pq[r];
      s += __shfl_xor(s, 1); s += __shfl_xor(s, 2);
      s += __shfl_xor(s, 4); s += __shfl_xor(s, 8);
      if (cg == 0) phil[r0 + rg * 4 + r] = s;
    }
  }
  __syncthreads();

  // ---- fused segmented reduction: 48 col-pairs x 8 sixteenths, b32 reads
  if (tid < 384) {
    const int p = tid % 48;          // column pair: cols 2p, 2p+1
    const int q8 = tid / 48;         // sixteenth: edges [q8*16, q8*16+16)
    const int s_lo = q8 * 16;
    const unsigned long long mk = bmask[s_lo >> 6];
    float a0 = 0.f, a1 = 0.f;
    bool clean = (q8 == 0) ? (vseq[0] != vseq[1])
                           : (((bmask[(s_lo - 1) >> 6] >> ((s_lo - 1) & 63)) & 1ull) != 0);
    for (int i = 0; i < 16; ++i) {
      const int e = s_lo + i;
      const half2v h2 = *(const half2v*)(actT + e * 104 + 2 * p);
      const float g = gl[e];
      a0 = fmaf(g, (float)h2[0], a0);
      a1 = fmaf(g, (float)h2[1], a1);
      const bool gend = ((mk >> (e & 63)) & 1ull) != 0;
      if (gend || i == 15) {
        const int node = vseq[e + 1];
        float* dst = wmo + (size_t)node * 96 + 2 * p;
        if (clean && gend) {
          *(float2*)dst = make_float2(a0, a1);
        } else {
          atomicAdd(dst, a0);
          atomicAdd(dst + 1, a1);
        }
        a0 = a1 = 0.f; clean = true;
      }
    }
  } else if (tid < 416) {
    // x-part: 4 comps x 8 sixteenths(16 edges)
    const int t2 = tid - 384;
    const int comp = t2 & 3, q8 = t2 >> 2;
    const int s_lo = q8 * 16;
    const unsigned long long mk = bmask[s_lo >> 6];
    float acc2 = 0.f;
    bool clean = (q8 == 0) ? (vseq[0] != vseq[1])
                           : (((bmask[(s_lo - 1) >> 6] >> ((s_lo - 1) & 63)) & 1ull) != 0);
    for (int i = 0; i < 16; ++i) {
      const int e = s_lo + i;
      acc2 = fmaf(phil[e], xjl[e * 4 + comp], acc2);
      const bool gend = ((mk >> (e & 63)) & 1ull) != 0;
      if (gend || i == 15) {
        const int node = vseq[e + 1];
        float* dst = svo + (size_t)node * 4 + comp;
        if (clean && gend) *dst = acc2; else atomicAdd(dst, acc2);
        acc2 = 0.f; clean = true;
      }
    }
  }
}

// ---------------------------------------------------------------------------
// K3 fused (MFMA f16), wave-local staging: only ONE barrier.
__global__ __launch_bounds__(256, 4) void k3ab(const float* __restrict__ h,
    const float* __restrict__ wmv,
    const unsigned short* __restrict__ Wh1p, const float* __restrict__ bh1,
    const unsigned short* __restrict__ Wh2p, const float* __restrict__ bh2,
    const float* __restrict__ x, const float* __restrict__ svm,
    const int* __restrict__ basep,
    float* __restrict__ hout, float* __restrict__ xout) {
  __shared__ __align__(16) unsigned short inT[64 * 200];   // reused as float[64][100]
  __shared__ __align__(16) unsigned short tmpT[64 * 104];
  const int tid = threadIdx.x;
  const int nb = blockIdx.x * 64;
  const int l = tid & 63, w = tid >> 6, cg = l & 15, rg = l >> 4;
  {
    const int r = w * 16 + (l & 15);
    const int cg2 = l >> 4;
    const int node = nb + r;
    const int nc = node < NN ? node : NN - 1;
    const float* hr = h + (long)nc * 96 + cg2 * 24;
    const float* wr = wmv + (long)nc * 96 + cg2 * 24;
    unsigned* dh = (unsigned*)inT + r * 100 + cg2 * 12;
    unsigned* dw = (unsigned*)inT + r * 100 + 48 + cg2 * 12;
    #pragma unroll
    for (int c = 0; c < 6; ++c) {
      const float4 v = *(const float4*)(hr + c * 4);
      dh[c * 2]     = pk2h(v.x, v.y);
      dh[c * 2 + 1] = pk2h(v.z, v.w);
      const float4 u = *(const float4*)(wr + c * 4);
      dw[c * 2]     = pk2h(u.x, u.y);
      dw[c * 2 + 1] = pk2h(u.z, u.w);
    }
  }
  // no barrier: inT rows wave-local
  {
    const unsigned short* ar = inT + (w * 16 + cg) * 200;
    half8v af[6];
    #pragma unroll
    for (int tk = 0; tk < 6; ++tk) af[tk] = *(const half8v*)(ar + tk * 32 + rg * 8);
    const half8v* Wp = (const half8v*)Wh1p;
    #pragma unroll
    for (int tn = 0; tn < 6; ++tn) {
      f32x4 acc = (f32x4){0.f, 0.f, 0.f, 0.f};
      #pragma unroll
      for (int tk = 0; tk < 6; ++tk)
        acc = __builtin_amdgcn_mfma_f32_16x16x32_f16(af[tk], Wp[(tk * 6 + tn) * 64 + l], acc, 0, 0, 0);
      const int col = tn * 16 + cg;
      const float b = bh1[col];
      #pragma unroll
      for (int r = 0; r < 4; ++r)
        tmpT[(w * 16 + rg * 4 + r) * 104 + col] = f2h_us(fmaxf(acc[r] + b, 0.f));
    }
  }
  // no barrier: tmpT rows wave-local
  {
    float* oT = (float*)inT;
    const unsigned short* mr = tmpT + (w * 16 + cg) * 104;
    const half8v mf0 = *(const half8v*)(mr + rg * 8);
    const half8v mf1 = *(const half8v*)(mr + 32 + rg * 8);
    const half8v mf2 = *(const half8v*)(mr + 64 + rg * 8);
    const half8v* Wp = (const half8v*)Wh2p;
    #pragma unroll
    for (int tn = 0; tn < 6; ++tn) {
      f32x4 acc = (f32x4){0.f, 0.f, 0.f, 0.f};
      acc = __builtin_amdgcn_mfma_f32_16x16x32_f16(mf0, Wp[(0 * 6 + tn) * 64 + l], acc, 0, 0, 0);
      acc = __builtin_amdgcn_mfma_f32_16x16x32_f16(mf1, Wp[(1 * 6 + tn) * 64 + l], acc, 0, 0, 0);
      acc = __builtin_amdgcn_mfma_f32_16x16x32_f16(mf2, Wp[(2 * 6 + tn) * 64 + l], acc, 0, 0, 0);
      const int col = tn * 16 + cg;
      const float b = bh2[col];
      #pragma unroll
      for (int r = 0; r < 4; ++r)
        oT[(w * 16 + rg * 4 + r) * 100 + col] = acc[r] + b;
    }
  }
  __syncthreads();
  {
    const int e = tid & 63, q = tid >> 6;
    const int node = nb + e;
    if (node < NN) {
      const float* src = (const float*)inT + e * 100 + q * 24;
      const float* hr = h + (size_t)node * 96 + q * 24;
      float* dst = hout + (size_t)node * 96 + q * 24;
      #pragma unroll
      for (int c = 0; c < 6; ++c) {
        const float4 s = *(const float4*)(src + c * 4);
        const float4 hv = *(const float4*)(hr + c * 4);
        *(float4*)(dst + c * 4) = make_float4(hv.x + s.x, hv.y + s.y, hv.z + s.z, hv.w + s.w);
      }
    }
  }
  if (tid < 64) {
    const int node = nb + tid;
    if (node < NN) {
      const int cnt = basep[node + 1] - basep[node];
      const float inv = cnt > 0 ? 1.f / (float)cnt : 0.f;
      const float4 s4 = *(const float4*)(svm + (long)node * 4);
      const float4 xv = *(const float4*)(x + (long)node * 4);
      *(float4*)(xout + (long)node * 4) =
          make_float4(xv.x + 0.005f * s4.x * inv, xv.y + 0.005f * s4.y * inv,
                      xv.z + 0.005f * s4.z * inv, xv.w + 0.005f * s4.w * inv);
    }
  }
}

// ---------------------------------------------------------------------------
extern "C" void kernel_launch(void* const* d_in, const int* in_sizes, int n_in,
                              void* d_out, int out_size, void* d_ws, size_t ws_size,
                              hipStream_t stream) {
  const float* x   = (const float*)d_in[0];
  const float* h   = (const float*)d_in[1];
  const int*   ei  = (const int*)d_in[2];
  const int*   ej  = (const int*)d_in[3];
  const float* We1 = (const float*)d_in[4];
  const float* be1 = (const float*)d_in[5];
  const float* We2 = (const float*)d_in[6];
  const float* be2 = (const float*)d_in[7];
  const float* Wm  = (const float*)d_in[8];
  const float* bm  = (const float*)d_in[9];
  const float* Wh1 = (const float*)d_in[10];
  const float* bh1 = (const float*)d_in[11];
  const float* Wh2 = (const float*)d_in[12];
  const float* bh2 = (const float*)d_in[13];
  const float* Wx1 = (const float*)d_in[14];
  const float* bx1 = (const float*)d_in[15];
  const float* Wx2 = (const float*)d_in[16];

  char* w = (char*)d_ws;
  unsigned short* Ahf  = (unsigned short*)w;                 //  9.6 MB
  unsigned short* Bhf  = (unsigned short*)(w + 9600000);     //  9.6 MB
  float* WMv  = (float*)(w + 19200000);                      // 19.2 MB
  float* SvM  = (float*)(w + 38400000);                      //  0.8 MB (contiguous after WMv)
  int*   cnt  = (int*)(w + 39200000);                        //  0.2 MB
  int*   base = (int*)(w + 39400000);                        //  0.2 MB (+4)
  int*   curs = (int*)(w + 39600064);                        //  0.2 MB
  unsigned short* We2p = (unsigned short*)(w + 39800064);    // 18 KB
  unsigned short* Wx1p = (unsigned short*)(w + 39818496);    // 18 KB
  unsigned short* We1p = (unsigned short*)(w + 39836928);    // 36 KB
  unsigned short* Wh1p = (unsigned short*)(w + 39873792);    // 36 KB
  unsigned short* Wh2p = (unsigned short*)(w + 39910656);    // 18 KB
  unsigned* WA2 = (unsigned*)(w + 39929088);                 // 192 B
  unsigned* WB2 = (unsigned*)(w + 39929280);                 // 192 B (pad to 39930112)
  int2*  epb  = (int2*)(w + 39930112);                       //  6.4 MB
  int*   pre  = (int*)(w + 46330112);                        //  0.2 MB
  int*   bsum = (int*)(w + 46530112);                        //  784 B

  float* hout = (float*)d_out;
  float* xout = hout + 4800000;

  hipMemsetAsync(cnt, 0, NN * sizeof(int), stream);
  kprep<<<NE / 256 + 72, 256, 0, stream>>>(ei, cnt, We1, We2, Wx1, Wh1, Wh2,
                                           We1p, We2p, Wx1p, Wh1p, Wh2p, WA2, WB2);
  kscanA<<<NB, 256, 0, stream>>>(cnt, pre, bsum);
  kscanBC<<<NB, 256, 0, stream>>>(pre, bsum, base, curs);
  kperm<<<NE / 256, 256, 0, stream>>>(ei, ej, curs, epb, WMv);
  k0_AB<<<782, 256, 0, stream>>>(h, We1p, be1, Ahf, Bhf);
  k1_edge<<<NE / TE, 512, 0, stream>>>(x, Ahf, Bhf, epb, WA2, WB2, We2p, be2,
                                       Wm, bm, Wx1p, bx1, Wx2, WMv, SvM);
  k3ab<<<782, 256, 0, stream>>>(h, WMv, Wh1p, bh1, Wh2p, bh2, x, SvM, base, hout, xout);
}

// Round 21
// 258.600 us; speedup vs baseline: 1.1988x; 1.0064x over previous
//
#include <hip/hip_runtime.h>
#include <math.h>

#define NN 50000
#define NE 800000
#define NB 196   // scan blocks (196*256 >= NN)
#define TE 128   // edges per k1 block

typedef __attribute__((ext_vector_type(8))) _Float16 half8v;
typedef __attribute__((ext_vector_type(2))) _Float16 half2v;
typedef __attribute__((ext_vector_type(4))) float f32x4;

__device__ __forceinline__ unsigned short f2h_us(float f) {
  const _Float16 h = (_Float16)f;
  return *(const unsigned short*)&h;
}
__device__ __forceinline__ unsigned pk2h(float a, float b) {
  half2v h; h[0] = (_Float16)a; h[1] = (_Float16)b;
  return *(unsigned*)&h;
}

// ---------------------------------------------------------------------------
// merged prep: blocks [0,3125) histogram edge_i; blocks [3125,3197) pack weights
__global__ void kprep(const int* __restrict__ ei, int* __restrict__ cnt,
                      const float* __restrict__ We1, const float* __restrict__ We2,
                      const float* __restrict__ Wx1, const float* __restrict__ Wh1,
                      const float* __restrict__ Wh2,
                      unsigned short* __restrict__ We1p, unsigned short* __restrict__ We2p,
                      unsigned short* __restrict__ Wx1p, unsigned short* __restrict__ Wh1p,
                      unsigned short* __restrict__ Wh2p, unsigned* __restrict__ WA2,
                      unsigned* __restrict__ WB2) {
  const int b = blockIdx.x;
  if (b < NE / 256) {
    const int i = b * 256 + threadIdx.x;
    atomicAdd(&cnt[ei[i]], 1);
    return;
  }
  const int t = (b - NE / 256) * 256 + threadIdx.x;   // 0..18431
  const int j = t & 7, lane = (t >> 3) & 63;
  const int kk = (lane >> 4) * 8 + j;
  const int nn = lane & 15;
  {  // We1p: K=96, N=192 (combined [top|bot])
    const int tile = t >> 9, tk = tile / 12, tn = tile % 12;
    const int k = tk * 32 + kk, n2 = tn * 16 + nn;
    const float v = (n2 < 96) ? We1[k * 96 + n2] : We1[(96 + k) * 96 + (n2 - 96)];
    We1p[t] = f2h_us(v);
  }
  {  // Wh1p: K=192, N=96
    const int tile = t >> 9, tk = tile / 6, tn = tile % 6;
    const int k = tk * 32 + kk, n = tn * 16 + nn;
    Wh1p[t] = f2h_us(Wh1[k * 96 + n]);
  }
  if (t < 9216) {  // We2p / Wx1p / Wh2p: K=96, N=96
    const int tile = t >> 9, tk = tile / 6, tn = tile % 6;
    const int k = tk * 32 + kk, n = tn * 16 + nn;
    We2p[t] = f2h_us(We2[k * 96 + n]);
    Wx1p[t] = f2h_us(Wx1[k * 96 + n]);
    Wh2p[t] = f2h_us(Wh2[k * 96 + n]);
  }
  if (t < 48) {  // psi weight rows as half2 pairs
    WA2[t] = pk2h(We1[192 * 96 + 2 * t], We1[192 * 96 + 2 * t + 1]);
    WB2[t] = pk2h(We1[193 * 96 + 2 * t], We1[193 * 96 + 2 * t + 1]);
  }
}

// scan A: per-block local exclusive scan + block sums
__global__ void kscanA(const int* __restrict__ cnt, int* __restrict__ pre,
                       int* __restrict__ bsum) {
  __shared__ int ps[256];
  const int b = blockIdx.x, t = threadIdx.x, idx = b * 256 + t;
  const int v = (idx < NN) ? cnt[idx] : 0;
  ps[t] = v;
  __syncthreads();
  for (int off = 1; off < 256; off <<= 1) {
    const int u = (t >= off) ? ps[t - off] : 0;
    __syncthreads();
    ps[t] += u;
    __syncthreads();
  }
  if (idx < NN) pre[idx] = ps[t] - v;
  if (t == 255) bsum[b] = ps[255];
}

// fused scan B+C: each block recomputes its block-offset from the 196 bsums
__global__ void kscanBC(const int* __restrict__ pre, const int* __restrict__ bsum,
                        int* __restrict__ base, int* __restrict__ cursor) {
  __shared__ int ws[4];
  const int b = blockIdx.x, t = threadIdx.x;
  int s = (t < b) ? bsum[t] : 0;   // b <= 195 < 256
  s += __shfl_xor(s, 1);  s += __shfl_xor(s, 2);  s += __shfl_xor(s, 4);
  s += __shfl_xor(s, 8);  s += __shfl_xor(s, 16); s += __shfl_xor(s, 32);
  if ((t & 63) == 0) ws[t >> 6] = s;
  __syncthreads();
  const int boff = ws[0] + ws[1] + ws[2] + ws[3];
  const int idx = b * 256 + t;
  if (idx < NN) {
    const int v = pre[idx] + boff;
    base[idx] = v;
    cursor[idx] = v;
  }
  if (idx == 0) base[NN] = NE;
}

// sort edges by vi into int2 pairs; also zeroes WMv/SvM (saves a memset dispatch)
__global__ void kperm(const int* __restrict__ ei, const int* __restrict__ ej,
                      int* __restrict__ cursor, int2* __restrict__ ep,
                      float* __restrict__ wz) {
  const int i = blockIdx.x * 256 + threadIdx.x;
  if (i < 625000) {   // 5,000,000 floats = WMv(4.8M) + SvM(0.2M), contiguous
    const float4 z = make_float4(0.f, 0.f, 0.f, 0.f);
    *(float4*)(wz + (size_t)i * 8) = z;
    *(float4*)(wz + (size_t)i * 8 + 4) = z;
  }
  const int vi = ei[i];
  const int pos = atomicAdd(&cursor[vi], 1);
  ep[pos] = make_int2(vi, ej[i]);
}

// ---------------------------------------------------------------------------
// K0 (MFMA f16): [A|B] = h @ [We1_top | We1_bot]; be1 folded into A half.
__global__ __launch_bounds__(256, 4) void k0_AB(const float* __restrict__ h,
                                                const unsigned short* __restrict__ We1p,
                                                const float* __restrict__ be1,
                                                unsigned short* __restrict__ Ahf,
                                                unsigned short* __restrict__ Bhf) {
  __shared__ __align__(16) unsigned short hbT[64 * 104];
  __shared__ __align__(16) unsigned short outT[64 * 200];
  const int tid = threadIdx.x;
  const int nb = blockIdx.x * 64;
  {
    const int e = tid & 63, q = tid >> 6;
    const int node = nb + e;
    const int nc = node < NN ? node : NN - 1;
    const float* hr = h + (long)nc * 96 + q * 24;
    unsigned* dst = (unsigned*)hbT + e * 52 + q * 12;
    #pragma unroll
    for (int c = 0; c < 6; ++c) {
      const float4 v = *(const float4*)(hr + c * 4);
      dst[c * 2]     = pk2h(v.x, v.y);
      dst[c * 2 + 1] = pk2h(v.z, v.w);
    }
  }
  __syncthreads();
  const int l = tid & 63, w = tid >> 6, cg = l & 15, rg = l >> 4;
  {
    const half8v* Wp = (const half8v*)We1p;
    const unsigned short* ar = hbT + (w * 16 + cg) * 104;
    const half8v af0 = *(const half8v*)(ar + rg * 8);
    const half8v af1 = *(const half8v*)(ar + 32 + rg * 8);
    const half8v af2 = *(const half8v*)(ar + 64 + rg * 8);
    #pragma unroll
    for (int tn = 0; tn < 12; ++tn) {
      f32x4 acc = (f32x4){0.f, 0.f, 0.f, 0.f};
      acc = __builtin_amdgcn_mfma_f32_16x16x32_f16(af0, Wp[(0 * 12 + tn) * 64 + l], acc, 0, 0, 0);
      acc = __builtin_amdgcn_mfma_f32_16x16x32_f16(af1, Wp[(1 * 12 + tn) * 64 + l], acc, 0, 0, 0);
      acc = __builtin_amdgcn_mfma_f32_16x16x32_f16(af2, Wp[(2 * 12 + tn) * 64 + l], acc, 0, 0, 0);
      const float bb = (tn < 6) ? be1[tn * 16 + cg] : 0.f;   // fold be1 into A half
      #pragma unroll
      for (int r = 0; r < 4; ++r)
        outT[(w * 16 + rg * 4 + r) * 200 + tn * 16 + cg] = f2h_us(acc[r] + bb);
    }
  }
  __syncthreads();
  {
    const int e = tid & 63, q = tid >> 6;
    const int node = nb + e;
    if (node < NN) {
      const unsigned* src = (const unsigned*)outT + e * 100;
      if (q < 2) {
        uint4* dA = (uint4*)(Ahf + (size_t)node * 96);
        #pragma unroll
        for (int i = 0; i < 6; ++i) dA[q * 6 + i] = *(const uint4*)(src + (q * 6 + i) * 4);
      } else {
        uint4* dB = (uint4*)(Bhf + (size_t)node * 96);
        #pragma unroll
        for (int i = 0; i < 6; ++i) dB[(q - 2) * 6 + i] = *(const uint4*)(src + 48 + ((q - 2) * 6 + i) * 4);
      }
    }
  }
}

// ---------------------------------------------------------------------------
// K1: 128 sorted edges/block, 512 threads (8 waves x 1 row-tile). FROZEN (R20).
__global__ __launch_bounds__(512, 6) void k1_edge(const float* __restrict__ x,
    const unsigned short* __restrict__ Ahf, const unsigned short* __restrict__ Bhf,
    const int2* __restrict__ ep,
    const unsigned* __restrict__ WA2, const unsigned* __restrict__ WB2,
    const unsigned short* __restrict__ We2p, const float* __restrict__ be2,
    const float* __restrict__ Wm, const float* __restrict__ bm,
    const unsigned short* __restrict__ Wx1p, const float* __restrict__ bx1,
    const float* __restrict__ Wx2,
    float* __restrict__ wmo, float* __restrict__ svo) {
  __shared__ __align__(16) unsigned short actT[TE * 104];
  __shared__ float gl[TE];
  __shared__ float phil[TE];
  __shared__ __align__(16) float xjl[TE * 4];
  __shared__ int vseq[TE + 2];
  __shared__ unsigned long long bmask[2];

  const int tid = threadIdx.x;
  const float bm0 = bm[0];
  const int tb = blockIdx.x * TE;

  // ---- phase 0: gather + h1 (packed fp16; thread: edge e2, feature quarter qf)
  {
    const int e2 = tid & 127, qf = tid >> 7;     // qf in [0,4): 24 features each
    const int fb = qf * 24;
    const int2 v2 = ep[tb + e2];
    const int vi = v2.x, vj = v2.y;
    const float4 xi = *(const float4*)(x + (long)vi * 4);
    const float4 xj = *(const float4*)(x + (long)vj * 4);
    if (qf == 0) {
      vseq[1 + e2] = vi;
      *(float4*)(xjl + e2 * 4) = xj;
    }
    if (tid == 0) {
      vseq[0] = (tb > 0) ? ep[tb - 1].x : -1;
      vseq[TE + 1] = (tb + TE < NE) ? ep[tb + TE].x : -1;
    }
    const float d0 = xi.x - xj.x, d1 = xi.y - xj.y, d2 = xi.z - xj.z, d3 = xi.w - xj.w;
    const float nrm = d0 * d0 - d1 * d1 - d2 * d2 - d3 * d3;
    const float prd = xi.x * xj.x - xi.y * xj.y - xi.z * xj.z - xi.w * xj.w;
    const float pn = copysignf(logf(fabsf(nrm) + 1.f), nrm);
    const float pp = copysignf(logf(fabsf(prd) + 1.f), prd);
    half2v pn2; pn2[0] = (_Float16)pn; pn2[1] = (_Float16)pn;
    half2v pp2; pp2[0] = (_Float16)pp; pp2[1] = (_Float16)pp;
    const half2v z2 = (half2v){(_Float16)0.f, (_Float16)0.f};
    const uint4* Ar = (const uint4*)(Ahf + (size_t)vi * 96 + fb);
    const uint4* Br = (const uint4*)(Bhf + (size_t)vj * 96 + fb);
    const half2v* wa2 = (const half2v*)(WA2 + fb / 2);
    const half2v* wb2 = (const half2v*)(WB2 + fb / 2);
    unsigned* arow = (unsigned*)actT + e2 * 52 + qf * 12;
    #pragma unroll
    for (int c = 0; c < 3; ++c) {
      const uint4 A4 = Ar[c], B4 = Br[c];
      const half2v* a2 = (const half2v*)&A4;
      const half2v* b2 = (const half2v*)&B4;
      #pragma unroll
      for (int k2 = 0; k2 < 4; ++k2) {
        half2v t = a2[k2] + b2[k2];
        t = pn2 * wa2[c * 4 + k2] + t;
        t = pp2 * wb2[c * 4 + k2] + t;
        t = __builtin_elementwise_max(t, z2);
        arow[c * 4 + k2] = *(unsigned*)&t;
      }
    }
  }
  __syncthreads();

  // ---- run-end boundary mask via ballot (waves 0,1)
  if (tid < TE) {
    const int pred = (vseq[1 + tid] != vseq[2 + tid]) ? 1 : 0;
    const unsigned long long mk = __ballot(pred);
    if ((tid & 63) == 0) bmask[tid >> 6] = mk;
  }

  const int l = tid & 63, w = tid >> 6;   // w in [0,8)
  const int cg = l & 15, rg = l >> 4;
  const int r0 = w * 16;                   // 1 row-tile per wave
  const half8v* Wp2 = (const half8v*)We2p;
  const half8v* Wpx = (const half8v*)Wx1p;

  // ---- GEMM2: m = relu(h1 @ We2 + be2); gate
  {
    half8v af[3];
    #pragma unroll
    for (int tk = 0; tk < 3; ++tk)
      af[tk] = *(const half8v*)(actT + (r0 + cg) * 104 + tk * 32 + rg * 8);
    f32x4 acc[6];
    #pragma unroll
    for (int tn = 0; tn < 6; ++tn) acc[tn] = (f32x4){0.f, 0.f, 0.f, 0.f};
    #pragma unroll
    for (int tk = 0; tk < 3; ++tk)
      #pragma unroll
      for (int tn = 0; tn < 6; ++tn)
        acc[tn] = __builtin_amdgcn_mfma_f32_16x16x32_f16(af[tk], Wp2[(tk * 6 + tn) * 64 + l], acc[tn], 0, 0, 0);
    float gp[4] = {0.f, 0.f, 0.f, 0.f};
    #pragma unroll
    for (int tn = 0; tn < 6; ++tn) {
      const int col = tn * 16 + cg;
      const float b = be2[col], wmw = Wm[col];
      #pragma unroll
      for (int r = 0; r < 4; ++r) {
        const float v = fmaxf(acc[tn][r] + b, 0.f);
        gp[r] = fmaf(v, wmw, gp[r]);
        actT[(r0 + rg * 4 + r) * 104 + col] = f2h_us(v);
      }
    }
    #pragma unroll
    for (int r = 0; r < 4; ++r) {
      float s = gp[r];
      s += __shfl_xor(s, 1); s += __shfl_xor(s, 2);
      s += __shfl_xor(s, 4); s += __shfl_xor(s, 8);
      if (cg == 0) gl[r0 + rg * 4 + r] = 1.f / (1.f + expf(-(s + bm0)));
    }
  }

  // no barrier: each wave reads only its own rows (m written by itself)

  // ---- GEMM3: phi = relu(m @ Wx1 + bx1) . Wx2
  {
    half8v af[3];
    #pragma unroll
    for (int tk = 0; tk < 3; ++tk)
      af[tk] = *(const half8v*)(actT + (r0 + cg) * 104 + tk * 32 + rg * 8);
    f32x4 acc[6];
    #pragma unroll
    for (int tn = 0; tn < 6; ++tn) acc[tn] = (f32x4){0.f, 0.f, 0.f, 0.f};
    #pragma unroll
    for (int tk = 0; tk < 3; ++tk)
      #pragma unroll
      for (int tn = 0; tn < 6; ++tn)
        acc[tn] = __builtin_amdgcn_mfma_f32_16x16x32_f16(af[tk], Wpx[(tk * 6 + tn) * 64 + l], acc[tn], 0, 0, 0);
    float pq[4] = {0.f, 0.f, 0.f, 0.f};
    #pragma unroll
    for (int tn = 0; tn < 6; ++tn) {
      const int col = tn * 16 + cg;
      const float b = bx1[col], wxw = Wx2[col];
      #pragma unroll
      for (int r = 0; r < 4; ++r)
        pq[r] = fmaf(fmaxf(acc[tn][r] + b, 0.f), wxw, pq[r]);
    }
    #pragma unroll
    for (int r = 0; r < 4; ++r) {
      float s = pq[r];
      s += __shfl_xor(s, 1); s += __shfl_xor(s, 2);
      s += __shfl_xor(s, 4); s += __shfl_xor(s, 8);
      if (cg == 0) phil[r0 + rg * 4 + r] = s;
    }
  }
  __syncthreads();

  // ---- fused segmented reduction: 48 col-pairs x 8 sixteenths, b32 reads
  if (tid < 384) {
    const int p = tid % 48;          // column pair: cols 2p, 2p+1
    const int q8 = tid / 48;         // sixteenth: edges [q8*16, q8*16+16)
    const int s_lo = q8 * 16;
    const unsigned long long mk = bmask[s_lo >> 6];
    float a0 = 0.f, a1 = 0.f;
    bool clean = (q8 == 0) ? (vseq[0] != vseq[1])
                           : (((bmask[(s_lo - 1) >> 6] >> ((s_lo - 1) & 63)) & 1ull) != 0);
    for (int i = 0; i < 16; ++i) {
      const int e = s_lo + i;
      const half2v h2 = *(const half2v*)(actT + e * 104 + 2 * p);
      const float g = gl[e];
      a0 = fmaf(g, (float)h2[0], a0);
      a1 = fmaf(g, (float)h2[1], a1);
      const bool gend = ((mk >> (e & 63)) & 1ull) != 0;
      if (gend || i == 15) {
        const int node = vseq[e + 1];
        float* dst = wmo + (size_t)node * 96 + 2 * p;
        if (clean && gend) {
          *(float2*)dst = make_float2(a0, a1);
        } else {
          atomicAdd(dst, a0);
          atomicAdd(dst + 1, a1);
        }
        a0 = a1 = 0.f; clean = true;
      }
    }
  } else if (tid < 416) {
    // x-part: 4 comps x 8 sixteenths(16 edges)
    const int t2 = tid - 384;
    const int comp = t2 & 3, q8 = t2 >> 2;
    const int s_lo = q8 * 16;
    const unsigned long long mk = bmask[s_lo >> 6];
    float acc2 = 0.f;
    bool clean = (q8 == 0) ? (vseq[0] != vseq[1])
                           : (((bmask[(s_lo - 1) >> 6] >> ((s_lo - 1) & 63)) & 1ull) != 0);
    for (int i = 0; i < 16; ++i) {
      const int e = s_lo + i;
      acc2 = fmaf(phil[e], xjl[e * 4 + comp], acc2);
      const bool gend = ((mk >> (e & 63)) & 1ull) != 0;
      if (gend || i == 15) {
        const int node = vseq[e + 1];
        float* dst = svo + (size_t)node * 4 + comp;
        if (clean && gend) *dst = acc2; else atomicAdd(dst, acc2);
        acc2 = 0.f; clean = true;
      }
    }
  }
}

// ---------------------------------------------------------------------------
// K3 fused (MFMA f16), wave-local staging, h kept in registers across the
// kernel (saves the 19.2 MB epilogue h re-read). One barrier total.
__global__ __launch_bounds__(256, 4) void k3ab(const float* __restrict__ h,
    const float* __restrict__ wmv,
    const unsigned short* __restrict__ Wh1p, const float* __restrict__ bh1,
    const unsigned short* __restrict__ Wh2p, const float* __restrict__ bh2,
    const float* __restrict__ x, const float* __restrict__ svm,
    const int* __restrict__ basep,
    float* __restrict__ hout, float* __restrict__ xout) {
  __shared__ __align__(16) unsigned short inT[64 * 200];   // reused as float[64][100]
  __shared__ __align__(16) unsigned short tmpT[64 * 104];
  const int tid = threadIdx.x;
  const int nb = blockIdx.x * 64;
  const int l = tid & 63, w = tid >> 6, cg = l & 15, rg = l >> 4;
  const int rr = w * 16 + (l & 15);      // staged row (wave-local)
  const int cg2 = l >> 4;                // staged col-group (24 cols)
  float4 hreg[6];                        // h values kept for epilogue
  {
    const int node = nb + rr;
    const int nc = node < NN ? node : NN - 1;
    const float* hr = h + (long)nc * 96 + cg2 * 24;
    const float* wr = wmv + (long)nc * 96 + cg2 * 24;
    unsigned* dh = (unsigned*)inT + rr * 100 + cg2 * 12;
    unsigned* dw = (unsigned*)inT + rr * 100 + 48 + cg2 * 12;
    #pragma unroll
    for (int c = 0; c < 6; ++c) {
      const float4 v = *(const float4*)(hr + c * 4);
      hreg[c] = v;
      dh[c * 2]     = pk2h(v.x, v.y);
      dh[c * 2 + 1] = pk2h(v.z, v.w);
      const float4 u = *(const float4*)(wr + c * 4);
      dw[c * 2]     = pk2h(u.x, u.y);
      dw[c * 2 + 1] = pk2h(u.z, u.w);
    }
  }
  // no barrier: inT rows wave-local
  {
    const unsigned short* ar = inT + (w * 16 + cg) * 200;
    half8v af[6];
    #pragma unroll
    for (int tk = 0; tk < 6; ++tk) af[tk] = *(const half8v*)(ar + tk * 32 + rg * 8);
    const half8v* Wp = (const half8v*)Wh1p;
    #pragma unroll
    for (int tn = 0; tn < 6; ++tn) {
      f32x4 acc = (f32x4){0.f, 0.f, 0.f, 0.f};
      #pragma unroll
      for (int tk = 0; tk < 6; ++tk)
        acc = __builtin_amdgcn_mfma_f32_16x16x32_f16(af[tk], Wp[(tk * 6 + tn) * 64 + l], acc, 0, 0, 0);
      const int col = tn * 16 + cg;
      const float b = bh1[col];
      #pragma unroll
      for (int r = 0; r < 4; ++r)
        tmpT[(w * 16 + rg * 4 + r) * 104 + col] = f2h_us(fmaxf(acc[r] + b, 0.f));
    }
  }
  // no barrier: tmpT rows wave-local
  {
    float* oT = (float*)inT;
    const unsigned short* mr = tmpT + (w * 16 + cg) * 104;
    const half8v mf0 = *(const half8v*)(mr + rg * 8);
    const half8v mf1 = *(const half8v*)(mr + 32 + rg * 8);
    const half8v mf2 = *(const half8v*)(mr + 64 + rg * 8);
    const half8v* Wp = (const half8v*)Wh2p;
    #pragma unroll
    for (int tn = 0; tn < 6; ++tn) {
      f32x4 acc = (f32x4){0.f, 0.f, 0.f, 0.f};
      acc = __builtin_amdgcn_mfma_f32_16x16x32_f16(mf0, Wp[(0 * 6 + tn) * 64 + l], acc, 0, 0, 0);
      acc = __builtin_amdgcn_mfma_f32_16x16x32_f16(mf1, Wp[(1 * 6 + tn) * 64 + l], acc, 0, 0, 0);
      acc = __builtin_amdgcn_mfma_f32_16x16x32_f16(mf2, Wp[(2 * 6 + tn) * 64 + l], acc, 0, 0, 0);
      const int col = tn * 16 + cg;
      const float b = bh2[col];
      #pragma unroll
      for (int r = 0; r < 4; ++r)
        oT[(w * 16 + rg * 4 + r) * 100 + col] = acc[r] + b;
    }
  }
  __syncthreads();
  {
    // epilogue on the SAME (rr, cg2) map: hout = hreg + oT slice
    const int node = nb + rr;
    if (node < NN) {
      const float* src = (const float*)inT + rr * 100 + cg2 * 24;
      float* dst = hout + (size_t)node * 96 + cg2 * 24;
      #pragma unroll
      for (int c = 0; c < 6; ++c) {
        const float4 s = *(const float4*)(src + c * 4);
        *(float4*)(dst + c * 4) =
            make_float4(hreg[c].x + s.x, hreg[c].y + s.y, hreg[c].z + s.z, hreg[c].w + s.w);
      }
    }
  }
  if (tid < 64) {
    const int node = nb + tid;
    if (node < NN) {
      const int cnt = basep[node + 1] - basep[node];
      const float inv = cnt > 0 ? 1.f / (float)cnt : 0.f;
      const float4 s4 = *(const float4*)(svm + (long)node * 4);
      const float4 xv = *(const float4*)(x + (long)node * 4);
      *(float4*)(xout + (long)node * 4) =
          make_float4(xv.x + 0.005f * s4.x * inv, xv.y + 0.005f * s4.y * inv,
                      xv.z + 0.005f * s4.z * inv, xv.w + 0.005f * s4.w * inv);
    }
  }
}

// ---------------------------------------------------------------------------
extern "C" void kernel_launch(void* const* d_in, const int* in_sizes, int n_in,
                              void* d_out, int out_size, void* d_ws, size_t ws_size,
                              hipStream_t stream) {
  const float* x   = (const float*)d_in[0];
  const float* h   = (const float*)d_in[1];
  const int*   ei  = (const int*)d_in[2];
  const int*   ej  = (const int*)d_in[3];
  const float* We1 = (const float*)d_in[4];
  const float* be1 = (const float*)d_in[5];
  const float* We2 = (const float*)d_in[6];
  const float* be2 = (const float*)d_in[7];
  const float* Wm  = (const float*)d_in[8];
  const float* bm  = (const float*)d_in[9];
  const float* Wh1 = (const float*)d_in[10];
  const float* bh1 = (const float*)d_in[11];
  const float* Wh2 = (const float*)d_in[12];
  const float* bh2 = (const float*)d_in[13];
  const float* Wx1 = (const float*)d_in[14];
  const float* bx1 = (const float*)d_in[15];
  const float* Wx2 = (const float*)d_in[16];

  char* w = (char*)d_ws;
  unsigned short* Ahf  = (unsigned short*)w;                 //  9.6 MB
  unsigned short* Bhf  = (unsigned short*)(w + 9600000);     //  9.6 MB
  float* WMv  = (float*)(w + 19200000);                      // 19.2 MB
  float* SvM  = (float*)(w + 38400000);                      //  0.8 MB (contiguous after WMv)
  int*   cnt  = (int*)(w + 39200000);                        //  0.2 MB
  int*   base = (int*)(w + 39400000);                        //  0.2 MB (+4)
  int*   curs = (int*)(w + 39600064);                        //  0.2 MB
  unsigned short* We2p = (unsigned short*)(w + 39800064);    // 18 KB
  unsigned short* Wx1p = (unsigned short*)(w + 39818496);    // 18 KB
  unsigned short* We1p = (unsigned short*)(w + 39836928);    // 36 KB
  unsigned short* Wh1p = (unsigned short*)(w + 39873792);    // 36 KB
  unsigned short* Wh2p = (unsigned short*)(w + 39910656);    // 18 KB
  unsigned* WA2 = (unsigned*)(w + 39929088);                 // 192 B
  unsigned* WB2 = (unsigned*)(w + 39929280);                 // 192 B (pad to 39930112)
  int2*  epb  = (int2*)(w + 39930112);                       //  6.4 MB
  int*   pre  = (int*)(w + 46330112);                        //  0.2 MB
  int*   bsum = (int*)(w + 46530112);                        //  784 B

  float* hout = (float*)d_out;
  float* xout = hout + 4800000;

  hipMemsetAsync(cnt, 0, NN * sizeof(int), stream);
  kprep<<<NE / 256 + 72, 256, 0, stream>>>(ei, cnt, We1, We2, Wx1, Wh1, Wh2,
                                           We1p, We2p, Wx1p, Wh1p, Wh2p, WA2, WB2);
  kscanA<<<NB, 256, 0, stream>>>(cnt, pre, bsum);
  kscanBC<<<NB, 256, 0, stream>>>(pre, bsum, base, curs);
  kperm<<<NE / 256, 256, 0, stream>>>(ei, ej, curs, epb, WMv);
  k0_AB<<<782, 256, 0, stream>>>(h, We1p, be1, Ahf, Bhf);
  k1_edge<<<NE / TE, 512, 0, stream>>>(x, Ahf, Bhf, epb, WA2, WB2, We2p, be2,
                                       Wm, bm, Wx1p, bx1, Wx2, WMv, SvM);
  k3ab<<<782, 256, 0, stream>>>(h, WMv, Wh1p, bh1, Wh2p, bh2, x, SvM, base, hout, xout);
}